// Round 13
// baseline (518.792 us; speedup 1.0000x reference)
//
#include <hip/hip_runtime.h>

// RBM CD-1 step on MI355X — round 21.
// = round-20 kernel (verified 479.7us, best) + split-K epilogue FUSION via
// per-tile arrival tickets (no new GEMM math; main loops byte-identical):
//  - gemm256<6> (G1a, K=3072 x2 z): both z-blocks store partials (z0->out,
//    z1->big), ACQ_REL agent atomicAdd on tile ticket; LAST arrival reads
//    partner partial (+32MB instead of epi's 64), adds in-register, then runs
//    the verified MODE-4 sampler machinery: sigmoid -> h_pred f32 / h_p bf16 /
//    hbin bf16 / ebuf -> hT u16 transposed / hbd colsums (64 slots).
//  - gemm256<7> (G5a, K=2048 x2 z): same, epilogue = h2T u8 + hbm (64 slots).
//  - epi_h_k deleted; tail_k sums hbd/hbm over 64 slots.
//  - tickets (2x128 ints in sums slack) zeroed by hipMemsetAsync per launch.
// Wait-free (last-arrival does work; no spin). Epilogues now overlap other
// tiles' main loops instead of serializing after the full GEMM.

typedef unsigned short u16;
typedef unsigned char u8;
typedef short s16x8 __attribute__((ext_vector_type(8)));
typedef float f32x4 __attribute__((ext_vector_type(4)));
typedef int i32x4 __attribute__((ext_vector_type(4)));
typedef u16 u16x4 __attribute__((ext_vector_type(4)));
typedef u16 u16x8 __attribute__((ext_vector_type(8)));
typedef u8 u8x8 __attribute__((ext_vector_type(8)));

constexpr int Bn = 8192, Vn = 2048, Hn = 1024;
constexpr size_t VH = (size_t)Vn * Hn;
constexpr size_t BH = (size_t)Bn * Hn;
constexpr size_t OUT_RECON = BH;                        // 8388608
constexpr size_t OUT_WGRAD = OUT_RECON + 1;             // 8388609
constexpr size_t OUT_VBG   = OUT_WGRAD + VH;            // 10485761
constexpr size_t OUT_HBG   = OUT_VBG + Vn;              // 10487809

__device__ __forceinline__ u16 f2bf(float x) {
  union { float f; unsigned u; } a; a.f = x;
  unsigned r = a.u + 0x7FFFu + ((a.u >> 16) & 1u);   // RNE
  return (u16)(r >> 16);
}
__device__ __forceinline__ float bf2f(u16 h) {
  union { unsigned u; float f; } a; a.u = ((unsigned)h) << 16;
  return a.f;
}
__device__ __forceinline__ float sigmoidf_(float x) {
  return 1.0f / (1.0f + __expf(-x));
}

using gptr_t = const unsigned int __attribute__((address_space(1)))*;
using lptr_t = unsigned int __attribute__((address_space(3)))*;

__device__ __forceinline__ void gload16(const void* g, void* l) {
  __builtin_amdgcn_global_load_lds((gptr_t)(unsigned long long)g,
                                   (lptr_t)(unsigned long long)l, 16, 0, 0);
}

// ---------------- merged prep kernel ----------------
// blocks [0,4096): v[B,V] f32 -> v_cat[B,2V]=[hi|lo], vT[V,B], vbd partials.
// blocks [4096,4608): w[V,H] f32 -> w_cat[V,2H], wT_cat[H,2V].
__global__ void prep_all_k(const float* __restrict__ v, u16* __restrict__ vcat,
                           u16* __restrict__ vT, float* __restrict__ vbd_p,
                           const float* __restrict__ w, u16* __restrict__ w_cat,
                           u16* __restrict__ wTc) {
  __shared__ u16 tile16[64][68];
  __shared__ float cs[16][64];
  __shared__ float tile32[64][65];
  const int bx = blockIdx.x;
  const int t = threadIdx.x;
  if (bx < 4096) {
    const int b0 = (bx & 127) << 6, c0 = (bx >> 7) << 6;
    const int rg = t >> 4;          // 0..15 row group
    const int cg = (t & 15) << 2;   // col *4
    float ca[4] = {0.f, 0.f, 0.f, 0.f};
#pragma unroll
    for (int i = 0; i < 4; ++i) {
      int r = rg + 16 * i;
      f32x4 x = *(const f32x4*)&v[(size_t)(b0 + r) * Vn + c0 + cg];
      u16x4 hi, lo;
#pragma unroll
      for (int j = 0; j < 4; ++j) {
        hi[j] = f2bf(x[j]);
        lo[j] = f2bf(x[j] - bf2f(hi[j]));
        tile16[r][cg + j] = hi[j];
        ca[j] += x[j];
      }
      *(u16x4*)&vcat[(size_t)(b0 + r) * (2 * Vn) + c0 + cg] = hi;
      *(u16x4*)&vcat[(size_t)(b0 + r) * (2 * Vn) + Vn + c0 + cg] = lo;
    }
#pragma unroll
    for (int j = 0; j < 4; ++j) cs[rg][cg + j] = ca[j];
    __syncthreads();
    if (t < 64) {
      float s = 0.f;
#pragma unroll
      for (int k = 0; k < 16; ++k) s += cs[k][t];
      vbd_p[(size_t)(bx & 127) * Vn + c0 + t] = s;   // [128][2048]
    }
#pragma unroll
    for (int s2 = 0; s2 < 2; ++s2) {
      int c = t >> 2;
      int seg = (t & 3) + 4 * s2;
      u16x8 pk;
#pragma unroll
      for (int i = 0; i < 8; ++i) pk[i] = tile16[seg * 8 + i][c];
      *(u16x8*)&vT[(size_t)(c0 + c) * Bn + b0 + seg * 8] = pk;
    }
  } else {
    const int wb = bx - 4096;
    const int v0 = (wb & 31) << 6, h0 = (wb >> 5) << 6;
    const int c = t & 63, r = t >> 6;
    for (int rr = r; rr < 64; rr += 4) {
      float x = w[(size_t)(v0 + rr) * Hn + h0 + c];
      tile32[rr][c] = x;
      u16 hi = f2bf(x), lo = f2bf(x - bf2f(hi));
      w_cat[(size_t)(v0 + rr) * (2 * Hn) + h0 + c]      = hi;
      w_cat[(size_t)(v0 + rr) * (2 * Hn) + Hn + h0 + c] = lo;
    }
    __syncthreads();
    for (int rr = r; rr < 64; rr += 4) {
      float x = tile32[c][rr];  // = w[v0+c][h0+rr]
      u16 hi = f2bf(x), lo = f2bf(x - bf2f(hi));
      size_t ro = (size_t)(h0 + rr) * (2 * Vn);
      wTc[ro + v0 + c]      = hi;
      wTc[ro + Vn + v0 + c] = lo;
    }
  }
}

// ---------------- GEMM 256x256, BK=32, 8 waves, 2-phase counted pipeline --
// MODE 4: G4 vk: A=hbin (dup), B=w_cat, K=2048 -> vk, vkT(u8), vbm (fused).
// MODE 6: G1a split-K x2 + FUSED epi1 (ticket): partials z0->f32out z1->redp;
//         last arrival: +partner, sigmoid -> h_pred(f32out)/h_p(bfout)/
//         hbin(aux16)/hT(tout, u16 transposed)/hbd(colp, 64 slots).
// MODE 7: G5a split-K x2 + FUSED epi5 (ticket): partials z0->f32out z1->redp;
//         last arrival: +partner, sigmoid/sample -> h2T(tout, u8)/hbm(colp).
// 'aux' carries the ticket array for modes 6/7.
template <int MODE>
__global__ __launch_bounds__(512) void gemm256(
    const u16* __restrict__ A, int lda, const u16* __restrict__ Bm, int ldb, int K,
    const float* __restrict__ bias, const float* __restrict__ uni,
    const float* __restrict__ aux, float* __restrict__ f32out,
    u16* __restrict__ bfout, const u16* __restrict__ aux16,
    float* __restrict__ redp, u16* __restrict__ tout, float* __restrict__ colp) {
  // As[4][256][32] at 0 (32768 u16), Bs[4][256][32] at 32768; 128 KB.
  // epilogue ebuf [256][264] (67584 u16 = 132 KB) aliases everything.
  __shared__ __align__(16) u16 smem[67584];
  const int t = threadIdx.x;
  const int lane = t & 63, wave = t >> 6;                // 8 waves
  const int wr = (wave >> 2) << 7;                       // 0 / 128
  const int wc = (wave & 3) << 6;                        // 0/64/128/192
  const int bidx = blockIdx.x, bidy = blockIdx.y, bidz = blockIdx.z;
  const int bm = bidx << 8, bn = bidy << 8;
  int kbeg = 0;
  if constexpr (MODE == 6 || MODE == 7) kbeg = bidz * K;
  f32x4 acc[8][4] = {};
  // staging (one gload = 512 thr x 16B = 128 rows x 64B): LDS row sr = t>>2,
  // granule t&3; fetch SWIZZLED global granule (t&3) ^ ((row>>1)&3) [r5 T2].
  const int sr = t >> 2;
  const int sc = (((t & 3) ^ ((t >> 3) & 3)) << 3);
  const u16* Ag  = A  + (size_t)(bm + sr) * lda + sc;
  const u16* Ag2 = Ag + (size_t)128 * lda;
  const u16* Bg  = Bm + (size_t)(bn + sr) * ldb + sc;
  const u16* Bg2 = Bg + (size_t)128 * ldb;
  const int fr = lane & 15, fg = lane >> 4;
  const int ga = ((fg ^ ((fr >> 1) & 3)) << 3);          // swizzled read granule

  auto acolf = [&](int k0) -> int {
    if constexpr (MODE == 6)      return (k0 < 2048) ? k0 : k0 - 2048;  // [hi|hi|lo]
    else if constexpr (MODE == 4) return k0 & 1023;
    else                          return k0 & 2047;                      // MODE 7
  };
  auto bcolf = [&](int k0) -> int {
    if constexpr (MODE == 6) return (k0 < 4096) ? k0 : k0 - 4096;       // [hi|lo|hi]
    else                     return k0;
  };
  auto stageA = [&](int kt) {
    const int k0 = kbeg + (kt << 5);
    const int acol = acolf(k0);
    u16* ad = smem + (kt & 3) * 8192 + wave * 512;       // wave-uniform base
    gload16(Ag + acol, ad);
    gload16(Ag2 + acol, ad + 4096);
  };
  auto stageB = [&](int kt) {
    const int k0 = kbeg + (kt << 5);
    const int bcol = bcolf(k0);
    u16* bd = smem + 32768 + (kt & 3) * 8192 + wave * 512;
    gload16(Bg + bcol, bd);
    gload16(Bg2 + bcol, bd + 4096);
  };
  // output/uni col-dim: MODE 4 -> Vn (u_v [B,V]); 6/7 -> Hn (u_h [B,H]).
  constexpr int NC = (MODE == 4) ? Vn : Hn;
  // epilogue-tile L2 prefetch: one probe per 128B line of the uni tile.
  auto pfl4 = [&](int ci) -> float {
    const int L = (ci << 9) + t;
    const int lpr = NC / 32;             // f32 lines per row (Vn:64? no) —
    // rows have NC*4 bytes; 128B lines per row = NC/32. For Vn=2048: 64... 
    // keep original mapping for MODE 4 (8 cols/line groups of 32 f32):
    return uni[(size_t)(bm + (L / (NC / 32))) * NC + bn +
               (L % (NC / 32)) * 32];
  };

  // 2-phase-per-tile counted pipeline (depth-4 slabs, pb = kt&3):
  // steady outstanding at phase-B vmcnt = 12 -> vmcnt(8) guards tile kt+1.
  const int NT = K >> 5;
  const int pfbeg = NT - 8;
  stageA(0); stageB(0); stageA(1); stageB(1); stageA(2); stageB(2);
  asm volatile("s_waitcnt vmcnt(8)" ::: "memory");
  __builtin_amdgcn_s_barrier();
  asm volatile("" ::: "memory");
  s16x8 bf[4], af[4];
  for (int kt = 0; kt < NT; ++kt) {
    const int pb = kt & 3;
    const u16* Ab = smem + pb * 8192;
    const u16* Bb = smem + 32768 + pb * 8192;
    const bool st = (kt < NT - 3);
    // ---- phase A: reads + A-stage + barrier + MFMA lo ----
#pragma unroll
    for (int n = 0; n < 4; ++n)
      bf[n] = *(const s16x8*)&Bb[(wc + n * 16 + fr) * 32 + ga];
#pragma unroll
    for (int m = 0; m < 4; ++m)
      af[m] = *(const s16x8*)&Ab[(wr + m * 16 + fr) * 32 + ga];
    if (st) stageA(kt + 3);
    if (kt >= pfbeg && kt < pfbeg + 4) {
      float pfv = pfl4(kt - pfbeg);
      asm volatile("" :: "v"(pfv));
    }
    __builtin_amdgcn_s_barrier();
    asm volatile("" ::: "memory");
    __builtin_amdgcn_s_setprio(1);
#pragma unroll
    for (int m = 0; m < 4; ++m)
#pragma unroll
      for (int n = 0; n < 4; ++n)
        acc[m][n] = __builtin_amdgcn_mfma_f32_16x16x32_bf16(af[m], bf[n], acc[m][n], 0, 0, 0);
    __builtin_amdgcn_s_setprio(0);
    // ---- phase B: reads + B-stage + vmcnt + barrier + MFMA hi ----
#pragma unroll
    for (int m = 0; m < 4; ++m)
      af[m] = *(const s16x8*)&Ab[(wr + (m + 4) * 16 + fr) * 32 + ga];
    if (st) stageB(kt + 3);
    if (kt < NT - 3) {
      asm volatile("s_waitcnt vmcnt(8)" ::: "memory");
    } else if (kt == NT - 3) {
      asm volatile("s_waitcnt vmcnt(4)" ::: "memory");
    } else if (kt == NT - 2) {
      asm volatile("s_waitcnt vmcnt(0)" ::: "memory");
    }
    __builtin_amdgcn_s_barrier();
    asm volatile("" ::: "memory");
    __builtin_amdgcn_s_setprio(1);
#pragma unroll
    for (int m = 0; m < 4; ++m)
#pragma unroll
      for (int n = 0; n < 4; ++n)
        acc[m + 4][n] = __builtin_amdgcn_mfma_f32_16x16x32_bf16(af[m], bf[n], acc[m + 4][n], 0, 0, 0);
    __builtin_amdgcn_s_setprio(0);
  }

  const int fq = lane >> 4;

  if constexpr (MODE == 6 || MODE == 7) {
    __syncthreads();
    // 1) store own partial (both-store protocol; z0 -> f32out, z1 -> redp)
    {
      float* mybuf = (bidz == 0) ? f32out : redp;
#pragma unroll
      for (int m = 0; m < 8; ++m)
#pragma unroll
        for (int n = 0; n < 4; ++n)
#pragma unroll
          for (int j = 0; j < 4; ++j) {
            int rl = wr + m * 16 + fq * 4 + j;
            int cl = wc + n * 16 + fr;
            mybuf[(size_t)(bm + rl) * NC + bn + cl] = acc[m][n][j];
          }
    }
    asm volatile("s_waitcnt vmcnt(0)" ::: "memory");
    __syncthreads();
    // 2) per-tile ticket; last of 2 arrivals runs the epilogue
    if (t == 0) {
      int* tick = (int*)aux;
      int old = __hip_atomic_fetch_add(&tick[bidx * 4 + bidy], 1,
                                       __ATOMIC_ACQ_REL, __HIP_MEMORY_SCOPE_AGENT);
      ((volatile int*)smem)[0] = (old & 1);
    }
    __syncthreads();
    const bool last = (((volatile int*)smem)[0] != 0);
    __syncthreads();
    if (!last) return;
    // 3) partner-add pass (rolling window, static &7 indices)
    {
      const float* pbuf = (bidz == 0) ? redp : f32out;
      float px[8][4];
      auto ld4p = [&](int ci, float* dst) {
        size_t e0 = (size_t)(bm + wr + fq * 4 + ((ci >> 2) << 4)) * NC
                  + (bn + wc + ((ci & 3) << 4) + fr);
        dst[0] = pbuf[e0];          dst[1] = pbuf[e0 + NC];
        dst[2] = pbuf[e0 + 2 * NC]; dst[3] = pbuf[e0 + 3 * NC];
      };
#pragma unroll
      for (int ci = 0; ci < 8; ++ci) ld4p(ci, px[ci]);
#pragma unroll
      for (int ci = 0; ci < 32; ++ci) {
        const int m = ci >> 2, n = ci & 3;
#pragma unroll
        for (int j = 0; j < 4; ++j) acc[m][n][j] += px[ci & 7][j];
        if (ci < 24) ld4p(ci + 8, px[ci & 7]);
      }
    }
    // 4) bias + sigmoid + sample (MODE-4 machinery), outputs per mode
    float bcol[4];
#pragma unroll
    for (int n = 0; n < 4; ++n) bcol[n] = bias[bn + wc + n * 16 + fr];
    float ux[8][4];
    auto ld4u = [&](int ci, float* dst) {
      size_t e0 = (size_t)(bm + wr + fq * 4 + ((ci >> 2) << 4)) * NC
                + (bn + wc + ((ci & 3) << 4) + fr);
      dst[0] = uni[e0];          dst[1] = uni[e0 + NC];
      dst[2] = uni[e0 + 2 * NC]; dst[3] = uni[e0 + 3 * NC];
    };
#pragma unroll
    for (int ci = 0; ci < 8; ++ci) ld4u(ci, ux[ci]);
#pragma unroll
    for (int m = 0; m < 8; ++m)
#pragma unroll
      for (int n = 0; n < 4; ++n)
#pragma unroll
        for (int j = 0; j < 4; ++j)
          acc[m][n][j] = sigmoidf_(acc[m][n][j] + bcol[n]);
    float csum[4] = {0.f, 0.f, 0.f, 0.f};
    u16* hbin_w = const_cast<u16*>(aux16);
#pragma unroll
    for (int ci = 0; ci < 32; ++ci) {
      const int m = ci >> 2, n = ci & 3;
      const int rl = wr + m * 16 + fq * 4;
      const int cl = wc + n * 16 + fr;
#pragma unroll
      for (int j = 0; j < 4; ++j) {
        float hp = acc[m][n][j];
        u16 qb = (hp > ux[ci & 7][j]) ? (u16)0x3F80 : (u16)0;
        smem[(rl + j) * 264 + cl] = qb;          // ebuf (feeds transpose)
        if constexpr (MODE == 6) {
          size_t e = (size_t)(bm + rl + j) * NC + bn + cl;
          f32out[e] = hp;                        // h_prediction
          bfout[e] = f2bf(hp);                   // h_p
          hbin_w[e] = qb;                        // hbin
          csum[n] += hp;                         // hbd (sum of h_p)
        } else {
          csum[n] += (qb ? 1.f : 0.f);           // hbm (count)
        }
      }
      if (ci < 24) ld4u(ci + 8, ux[ci & 7]);
    }
    // 5) colsums -> colp slots [0,64)
#pragma unroll
    for (int n = 0; n < 4; ++n) {
      float s = csum[n];
      s += __shfl_xor(s, 16);
      s += __shfl_xor(s, 32);
      if (fq == 0)
        colp[(size_t)(bidx * 2 + (wr >> 7)) * NC + (bn + wc + n * 16 + fr)] = s;
    }
    __syncthreads();   // ebuf fully written
    // 6) transposed writeout
    if constexpr (MODE == 6) {
      // hT u16, 64B-contiguous per thread
#pragma unroll
      for (int it = 0; it < 4; ++it) {
        int id = t + (it << 9);
        int c = id & 255;
        int q = id >> 8;                 // 0..7
#pragma unroll
        for (int i8_ = 0; i8_ < 4; ++i8_) {
          u16x8 pk;
#pragma unroll
          for (int i2 = 0; i2 < 8; ++i2)
            pk[i2] = smem[(q * 32 + i8_ * 8 + i2) * 264 + c];
          *(u16x8*)&tout[(size_t)(bn + c) * Bn + bm + q * 32 + i8_ * 8] = pk;
        }
      }
    } else {
      // h2T u8, 128B contiguous per thread
      u8* tout8 = (u8*)tout;
      const int c = t & 255;
      const int half = t >> 8;           // 0..1
#pragma unroll
      for (int i8_ = 0; i8_ < 16; ++i8_) {
        u8x8 pk;
#pragma unroll
        for (int i2 = 0; i2 < 8; ++i2)
          pk[i2] = smem[(half * 128 + i8_ * 8 + i2) * 264 + c] ? (u8)1 : (u8)0;
        *(u8x8*)&tout8[(size_t)(bn + c) * Bn + bm + half * 128 + i8_ * 8] = pk;
      }
    }
    return;
  }

  if constexpr (MODE == 4) {
    __syncthreads();   // all waves done with dbuf before ebuf writes
    float bcol[4];
#pragma unroll
    for (int n = 0; n < 4; ++n) bcol[n] = bias[bn + wc + n * 16 + fr];
    const size_t ebase = (size_t)(bm + wr + fq * 4) * NC + (bn + wc + fr);
    float ux[8][4];
    auto ld4 = [&](int ci, float* dst) {
      size_t e0 = ebase + (size_t)((ci >> 2) << 4) * NC + ((ci & 3) << 4);
      dst[0] = uni[e0];          dst[1] = uni[e0 + NC];
      dst[2] = uni[e0 + 2 * NC]; dst[3] = uni[e0 + 3 * NC];
    };
#pragma unroll
    for (int ci = 0; ci < 8; ++ci) ld4(ci, ux[ci]);
#pragma unroll
    for (int m = 0; m < 8; ++m)
#pragma unroll
      for (int n = 0; n < 4; ++n)
#pragma unroll
        for (int j = 0; j < 4; ++j)
          acc[m][n][j] = sigmoidf_(acc[m][n][j] + bcol[n]);
    float csum[4] = {0.f, 0.f, 0.f, 0.f};
#pragma unroll
    for (int ci = 0; ci < 32; ++ci) {
      const int m = ci >> 2, n = ci & 3;
      const int rl = wr + m * 16 + fq * 4;
      const int cl = wc + n * 16 + fr;
#pragma unroll
      for (int j = 0; j < 4; ++j) {
        u16 qb = (acc[m][n][j] > ux[ci & 7][j]) ? (u16)0x3F80 : (u16)0;
        smem[(rl + j) * 264 + cl] = qb;          // ebuf (feeds vk AND vkT)
        csum[n] += (qb ? 1.f : 0.f);
      }
      if (ci < 24) ld4(ci + 8, ux[ci & 7]);
    }
    // vbm partials: lane covers 32 rows; xor16+xor32 reduces fq -> 128 rows
#pragma unroll
    for (int n = 0; n < 4; ++n) {
      float s = csum[n];
      s += __shfl_xor(s, 16);
      s += __shfl_xor(s, 32);
      if (fq == 0)
        colp[(size_t)(bidx * 2 + (wr >> 7)) * NC + (bn + wc + n * 16 + fr)] = s;
    }
    __syncthreads();   // ebuf fully written
    // vk row-major writeout: coalesced u16x8 from ebuf.
#pragma unroll
    for (int it = 0; it < 16; ++it) {
      int id = t + (it << 9);
      int r = id >> 5;                   // 0..255
      int c0 = (id & 31) << 3;           // 0..248
      u16x8 pk = *(const u16x8*)&smem[r * 264 + c0];
      *(u16x8*)&bfout[(size_t)(bm + r) * NC + bn + c0] = pk;
    }
    // vkT u8 writeout: thread owns (col c, 128-row half) -> 128B contiguous.
    {
      u8* tout8 = (u8*)tout;
      const int c = t & 255;
      const int half = t >> 8;           // 0..1
#pragma unroll
      for (int i8_ = 0; i8_ < 16; ++i8_) {
        u8x8 pk;
#pragma unroll
        for (int i2 = 0; i2 < 8; ++i2)
          pk[i2] = smem[(half * 128 + i8_ * 8 + i2) * 264 + c] ? (u8)1 : (u8)0;
        *(u8x8*)&tout8[(size_t)(bn + c) * Bn + bm + half * 128 + i8_ * 8] = pk;
      }
    }
  }
}

// ---------------- i8 GEMM for G6 (binary x binary, exact) -----------------
__global__ __launch_bounds__(512) void gemm_i8_k(
    const u8* __restrict__ A, const u8* __restrict__ Bm,
    float* __restrict__ out0, float* __restrict__ out4) {
  __shared__ __align__(16) u8 smem[131072];
  const int t = threadIdx.x;
  const int lane = t & 63, wave = t >> 6;
  const int wr = (wave >> 2) << 7;
  const int wc = (wave & 3) << 6;
  const int orig = blockIdx.x + (blockIdx.y << 3) + (blockIdx.z << 5);
  const int bidz = orig & 7;
  const int rr = orig >> 3;
  const int bidx = rr & 7, bidy = rr >> 3;
  const int bm = bidx << 8, bn = bidy << 8;
  const int kbeg = bidz << 10;           // 1024 u8 per z-slice
  float* pout = ((bidz < 4) ? out0 : out4) + (size_t)(bidz & 3) * VH;
  i32x4 acc[8][4] = {};
  const int sr = t >> 2;
  const int sc = (((t & 3) ^ ((t >> 3) & 3)) << 4);    // 16B granule (bytes)
  const u8* Ag  = A  + (size_t)(bm + sr) * Bn + sc;
  const u8* Ag2 = Ag + (size_t)128 * Bn;
  const u8* Bg  = Bm + (size_t)(bn + sr) * Bn + sc;
  const u8* Bg2 = Bg + (size_t)128 * Bn;
  const int fr = lane & 15, fg = lane >> 4;
  const int ga = ((fg ^ ((fr >> 1) & 3)) << 4);        // bytes

  auto stageA = [&](int kt) {
    u8* ad = smem + (kt & 3) * 16384 + wave * 1024;
    gload16(Ag + kbeg + (kt << 6), ad);
    gload16(Ag2 + kbeg + (kt << 6), ad + 8192);
  };
  auto stageB = [&](int kt) {
    u8* bd = smem + 65536 + (kt & 3) * 16384 + wave * 1024;
    gload16(Bg + kbeg + (kt << 6), bd);
    gload16(Bg2 + kbeg + (kt << 6), bd + 8192);
  };

  constexpr int NT = 16;
  stageA(0); stageB(0); stageA(1); stageB(1); stageA(2); stageB(2);
  asm volatile("s_waitcnt vmcnt(8)" ::: "memory");
  __builtin_amdgcn_s_barrier();
  asm volatile("" ::: "memory");
  i32x4 bf[4], af[4];
  for (int kt = 0; kt < NT; ++kt) {
    const u8* Ab = smem + (kt & 3) * 16384;
    const u8* Bb = smem + 65536 + (kt & 3) * 16384;
    const bool st = (kt < NT - 3);
    // phase A
#pragma unroll
    for (int n = 0; n < 4; ++n)
      bf[n] = *(const i32x4*)&Bb[(wc + n * 16 + fr) * 64 + ga];
#pragma unroll
    for (int m = 0; m < 4; ++m)
      af[m] = *(const i32x4*)&Ab[(wr + m * 16 + fr) * 64 + ga];
    if (st) stageA(kt + 3);
    __builtin_amdgcn_s_barrier();
    asm volatile("" ::: "memory");
    __builtin_amdgcn_s_setprio(1);
#pragma unroll
    for (int m = 0; m < 4; ++m)
#pragma unroll
      for (int n = 0; n < 4; ++n)
        acc[m][n] = __builtin_amdgcn_mfma_i32_16x16x64_i8(af[m], bf[n], acc[m][n], 0, 0, 0);
    __builtin_amdgcn_s_setprio(0);
    // phase B
#pragma unroll
    for (int m = 0; m < 4; ++m)
      af[m] = *(const i32x4*)&Ab[(wr + (m + 4) * 16 + fr) * 64 + ga];
    if (st) stageB(kt + 3);
    if (kt < NT - 3) {
      asm volatile("s_waitcnt vmcnt(8)" ::: "memory");
    } else if (kt == NT - 3) {
      asm volatile("s_waitcnt vmcnt(4)" ::: "memory");
    } else if (kt == NT - 2) {
      asm volatile("s_waitcnt vmcnt(0)" ::: "memory");
    }
    __builtin_amdgcn_s_barrier();
    asm volatile("" ::: "memory");
    __builtin_amdgcn_s_setprio(1);
#pragma unroll
    for (int m = 0; m < 4; ++m)
#pragma unroll
      for (int n = 0; n < 4; ++n)
        acc[m + 4][n] = __builtin_amdgcn_mfma_i32_16x16x64_i8(af[m], bf[n], acc[m + 4][n], 0, 0, 0);
    __builtin_amdgcn_s_setprio(0);
  }

  const int fq = lane >> 4;
#pragma unroll
  for (int m = 0; m < 8; ++m)
#pragma unroll
    for (int n = 0; n < 4; ++n)
#pragma unroll
      for (int j = 0; j < 4; ++j) {
        int rl = wr + m * 16 + fq * 4 + j;
        int cl = wc + n * 16 + fr;
        pout[(size_t)(bm + rl) * Hn + bn + cl] = (float)acc[m][n][j];
      }
}

// ---------------- merged G2+G3 (512 blocks, one launch) -------------------
__global__ __launch_bounds__(512) void g23_k(
    const u16* __restrict__ A2, const u16* __restrict__ B2,
    const u16* __restrict__ aux16, const float* __restrict__ bias2,
    float* __restrict__ redp2,
    const u16* __restrict__ A3, const u16* __restrict__ B3,
    float* __restrict__ out30, float* __restrict__ out34) {
  __shared__ __align__(16) u16 smem[65536];
  const int t = threadIdx.x;
  const int lane = t & 63, wave = t >> 6;
  const int wr = (wave >> 2) << 7;
  const int wc = (wave & 3) << 6;
  const int flat = blockIdx.x;
  const bool isG2 = (flat < 256);
  int bidx, bidy, bidz = 0;
  const u16 *Abase, *Bbase;
  int lda, ldb;
  if (isG2) {
    bidx = flat & 31; bidy = flat >> 5;
    Abase = A2; Bbase = B2; lda = Hn; ldb = 2 * Hn;
  } else {
    const int orig = flat - 256;
    bidz = orig & 7;
    const int rr = orig >> 3;          // 0..31 rank within XCD
    bidx = rr & 7; bidy = rr >> 3;
    Abase = A3 + (size_t)bidz * 1024;
    Bbase = B3 + (size_t)bidz * 1024;
    lda = Bn; ldb = Bn;
  }
  const int bm = bidx << 8, bn = bidy << 8;
  f32x4 acc[8][4] = {};
  const int sr = t >> 2;
  const int sc = (((t & 3) ^ ((t >> 3) & 3)) << 3);
  const u16* Ag  = Abase + (size_t)(bm + sr) * lda + sc;
  const u16* Ag2 = Ag + (size_t)128 * lda;
  const u16* Bg  = Bbase + (size_t)(bn + sr) * ldb + sc;
  const u16* Bg2 = Bg + (size_t)128 * ldb;
  const int fr = lane & 15, fg = lane >> 4;
  const int ga = ((fg ^ ((fr >> 1) & 3)) << 3);

  auto stageA = [&](int kt) {
    u16* ad = smem + (kt & 3) * 8192 + wave * 512;
    gload16(Ag + (kt << 5), ad);
    gload16(Ag2 + (kt << 5), ad + 4096);
  };
  auto stageB = [&](int kt) {
    u16* bd = smem + 32768 + (kt & 3) * 8192 + wave * 512;
    gload16(Bg + (kt << 5), bd);
    gload16(Bg2 + (kt << 5), bd + 4096);
  };
  auto pfl2 = [&](int ci) -> unsigned {
    const int L = (ci << 9) + t;         // 0..1023
    return (unsigned)aux16[(size_t)(bm + (L >> 2)) * 4096 + bn + ((L & 3) << 6)];
  };

  constexpr int NT = 32;
  stageA(0); stageB(0); stageA(1); stageB(1); stageA(2); stageB(2);
  asm volatile("s_waitcnt vmcnt(8)" ::: "memory");
  __builtin_amdgcn_s_barrier();
  asm volatile("" ::: "memory");
  s16x8 bf[4], af[4];
  for (int kt = 0; kt < NT; ++kt) {
    const int pb = kt & 3;
    const u16* Ab = smem + pb * 8192;
    const u16* Bb = smem + 32768 + pb * 8192;
    const bool st = (kt < NT - 3);
    // phase A
#pragma unroll
    for (int n = 0; n < 4; ++n)
      bf[n] = *(const s16x8*)&Bb[(wc + n * 16 + fr) * 32 + ga];
#pragma unroll
    for (int m = 0; m < 4; ++m)
      af[m] = *(const s16x8*)&Ab[(wr + m * 16 + fr) * 32 + ga];
    if (st) stageA(kt + 3);
    if (isG2 && kt >= NT - 8 && kt < NT - 6) {
      unsigned pfv = pfl2(kt - (NT - 8));
      asm volatile("" :: "v"(pfv));
    }
    __builtin_amdgcn_s_barrier();
    asm volatile("" ::: "memory");
    __builtin_amdgcn_s_setprio(1);
#pragma unroll
    for (int m = 0; m < 4; ++m)
#pragma unroll
      for (int n = 0; n < 4; ++n)
        acc[m][n] = __builtin_amdgcn_mfma_f32_16x16x32_bf16(af[m], bf[n], acc[m][n], 0, 0, 0);
    __builtin_amdgcn_s_setprio(0);
    // phase B
#pragma unroll
    for (int m = 0; m < 4; ++m)
      af[m] = *(const s16x8*)&Ab[(wr + (m + 4) * 16 + fr) * 32 + ga];
    if (st) stageB(kt + 3);
    if (kt < NT - 3) {
      asm volatile("s_waitcnt vmcnt(8)" ::: "memory");
    } else if (kt == NT - 3) {
      asm volatile("s_waitcnt vmcnt(4)" ::: "memory");
    } else if (kt == NT - 2) {
      asm volatile("s_waitcnt vmcnt(0)" ::: "memory");
    }
    __builtin_amdgcn_s_barrier();
    asm volatile("" ::: "memory");
    __builtin_amdgcn_s_setprio(1);
#pragma unroll
    for (int m = 0; m < 4; ++m)
#pragma unroll
      for (int n = 0; n < 4; ++n)
        acc[m + 4][n] = __builtin_amdgcn_mfma_f32_16x16x32_bf16(af[m], bf[n], acc[m + 4][n], 0, 0, 0);
    __builtin_amdgcn_s_setprio(0);
  }

  const int fq = lane >> 4;
  if (isG2) {
    // pipelined recon vs v_cat-hi (u16, stride 4096), depth-8 window (&7).
    float bcol[4];
#pragma unroll
    for (int n = 0; n < 4; ++n) bcol[n] = bias2[bn + wc + n * 16 + fr];
    const size_t ebase = (size_t)(bm + wr + fq * 4) * 4096 + (bn + wc + fr);
    float ax[8][4];
    auto ld4 = [&](int ci, float* dst) {
      size_t e0 = ebase + (size_t)((ci >> 2) << 4) * 4096 + ((ci & 3) << 4);
      dst[0] = bf2f(aux16[e0]);            dst[1] = bf2f(aux16[e0 + 4096]);
      dst[2] = bf2f(aux16[e0 + 2 * 4096]); dst[3] = bf2f(aux16[e0 + 3 * 4096]);
    };
#pragma unroll
    for (int ci = 0; ci < 8; ++ci) ld4(ci, ax[ci]);
#pragma unroll
    for (int m = 0; m < 8; ++m)
#pragma unroll
      for (int n = 0; n < 4; ++n)
#pragma unroll
        for (int j = 0; j < 4; ++j)
          acc[m][n][j] = sigmoidf_(acc[m][n][j] + bcol[n]);
    float lsum = 0.f;
#pragma unroll
    for (int ci = 0; ci < 32; ++ci) {
      const int m = ci >> 2, n = ci & 3;
#pragma unroll
      for (int j = 0; j < 4; ++j) lsum += fabsf(ax[ci & 7][j] - acc[m][n][j]);
      if (ci < 24) ld4(ci + 8, ax[ci & 7]);
    }
#pragma unroll
    for (int off = 32; off > 0; off >>= 1) lsum += __shfl_down(lsum, off);
    __syncthreads();
    float* redlds = (float*)smem;
    if (lane == 0) redlds[wave] = lsum;
    __syncthreads();
    if (t == 0) {
      float s = 0.f;
#pragma unroll
      for (int wv = 0; wv < 8; ++wv) s += redlds[wv];
      redp2[(size_t)bidy * 32 + bidx] = s;
    }
  } else {
    float* pout = ((bidz < 4) ? out30 : out34) + (size_t)(bidz & 3) * VH;
#pragma unroll
    for (int m = 0; m < 8; ++m)
#pragma unroll
      for (int n = 0; n < 4; ++n)
#pragma unroll
        for (int j = 0; j < 4; ++j) {
          int rl = wr + m * 16 + fq * 4 + j;
          int cl = wc + n * 16 + fr;
          pout[(size_t)(bm + rl) * Hn + bn + cl] = acc[m][n][j];
        }
  }
}

// out[i] = sum_{z<8} p[z][i]  (scalar stores: out base misaligned)
__global__ void reduce8_k(const float* __restrict__ p, float* __restrict__ out) {
  size_t e = ((size_t)blockIdx.x * 256 + threadIdx.x) * 4;
  f32x4 r = {};
#pragma unroll
  for (int z = 0; z < 8; ++z) r += *(const f32x4*)&p[(size_t)z * VH + e];
  out[e + 0] = r[0]; out[e + 1] = r[1]; out[e + 2] = r[2]; out[e + 3] = r[3];
}

// merged tail: blocks <2048 = reduce8s (w_grad = model partials - data grad),
// blocks >=2048 (8) = finalize. hbd/hbm now 64 slots (fused epilogues).
__global__ void tail_k(const float* __restrict__ pa, const float* __restrict__ pb,
                       const float* __restrict__ sums, float* __restrict__ out) {
  const int b = blockIdx.x;
  float* outw = out + OUT_WGRAD;
  if (b < 2048) {
    size_t e = ((size_t)b * 256 + threadIdx.x) * 4;
    f32x4 r = {};
#pragma unroll
    for (int z = 0; z < 4; ++z) r += *(const f32x4*)&pa[(size_t)z * VH + e];
#pragma unroll
    for (int z = 0; z < 4; ++z) r += *(const f32x4*)&pb[(size_t)z * VH + e];
    float s0 = outw[e + 0], s1 = outw[e + 1], s2 = outw[e + 2], s3 = outw[e + 3];
    outw[e + 0] = r[0] - s0; outw[e + 1] = r[1] - s1;
    outw[e + 2] = r[2] - s2; outw[e + 3] = r[3] - s3;
  } else {
    const int i = (b - 2048) * 256 + threadIdx.x;   // 0..2047
    const float* recon_p = sums;                 // 256
    const float* vbd = sums + 1024;              // 128 x 2048
    const float* hbd = vbd + 128 * 2048;         // 64 x 1024 used
    const float* vbm = hbd + 128 * 1024;         // 64 x 2048
    const float* hbm = vbm + 128 * 2048;         // 64 x 1024 used
    if (i < 2048) {
      float d = 0.f, m = 0.f;
      for (int k = 0; k < 128; ++k) d += vbd[k * 2048 + i];
      for (int k = 0; k < 64; ++k)  m += vbm[k * 2048 + i];
      out[OUT_VBG + i] = m - d;
    }
    if (i < 1024) {
      float d = 0.f, m = 0.f;
      for (int k = 0; k < 64; ++k) { d += hbd[k * 1024 + i]; m += hbm[k * 1024 + i]; }
      out[OUT_HBG + i] = m - d;
    }
    if (i == 0) {
      float s = 0.f;
      for (int k = 0; k < 256; ++k) s += recon_p[k];
      out[OUT_RECON] = s * (1.0f / 16777216.0f);  // /(B*V)
    }
  }
}

extern "C" void kernel_launch(void* const* d_in, const int* in_sizes, int n_in,
                              void* d_out, int out_size, void* d_ws, size_t ws_size,
                              hipStream_t stream) {
  (void)in_sizes; (void)n_in; (void)out_size;
  const float* v   = (const float*)d_in[0];
  const float* w   = (const float*)d_in[1];
  const float* vb  = (const float*)d_in[2];
  const float* hb  = (const float*)d_in[3];
  const float* u_h = (const float*)d_in[4];
  const float* u_v = (const float*)d_in[5];
  float* out = (float*)d_out;
  char* ws = (char*)d_ws;
  if (ws_size < 204734464ULL) return;

  float* sums    = (float*)ws;               // 3.25 MiB region
  float* recon_p = sums;                     // 256
  int*   tickG1  = (int*)(sums + 256);       // 128 ints
  int*   tickG5  = (int*)(sums + 384);       // 128 ints
  float* vbd_p   = sums + 1024;              // 128*2048
  float* hbd_p   = vbd_p + 128 * 2048;       // 64*1024 used
  float* vbm_p   = hbd_p + 128 * 1024;       // 64*2048
  float* hbm_p   = vbm_p + 128 * 2048;       // 64*1024 used
  char* p = ws + 3407872;
  u16* v_cat  = (u16*)p;  p += (size_t)Bn * 2 * Vn * 2;   // 64 MiB [B,2V]
  u16* wT_cat = (u16*)p;  p += (size_t)Hn * 2 * Vn * 2;   // 8 MiB [H,2V]
  u16* w_cat  = (u16*)p;  p += (size_t)Vn * 2 * Hn * 2;   // 8 MiB [V,2H]
  u16* h_p    = (u16*)p;  p += BH * 2;                    // 16 MiB [B,H]
  u16* hbin   = (u16*)p;  p += BH * 2;                    // 16 MiB [B,H]
  u16* vT     = (u16*)p;  p += (size_t)Vn * Bn * 2;       // 32 MiB [V,B]
  u16* hT     = (u16*)p;  p += (size_t)Hn * Bn * 2;       // 16 MiB [H,B]
  float* big  = (float*)p;                                // 32 MiB time-shared
  u16* vk   = v_cat;            // v_cat dead after g23 (G3 partials overwrite)
  u8*  vkT8 = (u8*)vT;          // vT dead after g23; u8 vkT (16 MiB used)
  u8*  h2T8 = (u8*)hT;          // hT dead after g23; u8 h2T (8 MiB used)
  float* vcat_f = (float*)v_cat;   // 64 MiB: G3's 8 partials
  float* hpbuf  = (float*)h_p;     // h_p+hbin region (32 MiB) as f32 partials
  float* outW   = out + OUT_WGRAD;

  hipMemsetAsync(tickG1, 0, 256 * sizeof(int), stream);   // both ticket arrays
  prep_all_k<<<4608, 256, 0, stream>>>(v, v_cat, vT, vbd_p, w, w_cat, wT_cat);
  // G1a + fused epi1: partials z0->out, z1->big; last arrival emits
  // h_pred(out)/h_p/hbin/hT/hbd.
  gemm256<6><<<dim3(32, 4, 2), 512, 0, stream>>>(
      v_cat, 2 * Vn, wT_cat, 2 * Vn, 3072, hb, u_h, (const float*)tickG1,
      out, h_p, hbin, big, hT, hbd_p);
  // merged G2 (recon) + G3 (w_data_grad partials): 512 blocks, one launch
  g23_k<<<512, 512, 0, stream>>>(
      h_p, w_cat, v_cat, vb, recon_p,
      vT, hT, vcat_f, vcat_f + 4 * VH);
  reduce8_k<<<2048, 256, 0, stream>>>(vcat_f, outW);   // outW = data-grad sum
  // G4: vk/vkT(u8) + vbm partials (fused sample+transpose epilogue)
  gemm256<4><<<dim3(32, 8), 512, 0, stream>>>(
      hbin, Hn, w_cat, 2 * Hn, 2 * Hn, vb, u_v, nullptr,
      nullptr, vk, nullptr, nullptr, (u16*)vkT8, vbm_p);
  // G5a + fused epi5: partials z0->hpbuf, z1->big; last arrival emits
  // h2T(u8)/hbm.
  gemm256<7><<<dim3(32, 4, 2), 512, 0, stream>>>(
      vk, Vn, wT_cat, 2 * Vn, 2048, hb, u_h + BH, (const float*)tickG5,
      hpbuf, nullptr, nullptr, big, (u16*)h2T8, hbm_p);
  // G6: w_model_grad partials via i8 MFMA (exact; split-K x8)
  gemm_i8_k<<<dim3(8, 4, 8), 512, 0, stream>>>(vkT8, h2T8, hpbuf, big);
  // merged reduce8s + finalize
  tail_k<<<2056, 256, 0, stream>>>(hpbuf, big, sums, out);
}

// Round 14
// 484.032 us; speedup vs baseline: 1.0718x; 1.0718x over previous
//
#include <hip/hip_runtime.h>

// RBM CD-1 step on MI355X — round 22 = REVERT to round-20 (verified 479.7us).
// r21's ticket-fused split-K epilogues (MODE 6/7) regressed +39us: VGPR
// 92->128 (MfmaUtil 45.7->26), epilogue ran on only 128 last-arrival blocks
// at 1 block/CU (half the CUs idle), and scalar output stores + the partial
// store->atomic->reload roundtrip inflated traffic (FETCH 136/WRITE 149MB).
// Measured anti-pattern: ticket-fused epilogues on 1-block/CU GEMMs.
// Structure (r20): 256x256 BK=32 8-wave 2-phase counted pipeline; i8 G6
// (binary operands, exact); merged g23/tail; separate epi_h kernels.

typedef unsigned short u16;
typedef unsigned char u8;
typedef short s16x8 __attribute__((ext_vector_type(8)));
typedef float f32x4 __attribute__((ext_vector_type(4)));
typedef int i32x4 __attribute__((ext_vector_type(4)));
typedef u16 u16x4 __attribute__((ext_vector_type(4)));
typedef u16 u16x8 __attribute__((ext_vector_type(8)));
typedef u8 u8x8 __attribute__((ext_vector_type(8)));

constexpr int Bn = 8192, Vn = 2048, Hn = 1024;
constexpr size_t VH = (size_t)Vn * Hn;
constexpr size_t BH = (size_t)Bn * Hn;
constexpr size_t OUT_RECON = BH;                        // 8388608
constexpr size_t OUT_WGRAD = OUT_RECON + 1;             // 8388609
constexpr size_t OUT_VBG   = OUT_WGRAD + VH;            // 10485761
constexpr size_t OUT_HBG   = OUT_VBG + Vn;              // 10487809

__device__ __forceinline__ u16 f2bf(float x) {
  union { float f; unsigned u; } a; a.f = x;
  unsigned r = a.u + 0x7FFFu + ((a.u >> 16) & 1u);   // RNE
  return (u16)(r >> 16);
}
__device__ __forceinline__ float bf2f(u16 h) {
  union { unsigned u; float f; } a; a.u = ((unsigned)h) << 16;
  return a.f;
}
__device__ __forceinline__ float sigmoidf_(float x) {
  return 1.0f / (1.0f + __expf(-x));
}

using gptr_t = const unsigned int __attribute__((address_space(1)))*;
using lptr_t = unsigned int __attribute__((address_space(3)))*;

__device__ __forceinline__ void gload16(const void* g, void* l) {
  __builtin_amdgcn_global_load_lds((gptr_t)(unsigned long long)g,
                                   (lptr_t)(unsigned long long)l, 16, 0, 0);
}

// ---------------- merged prep kernel ----------------
// blocks [0,4096): v[B,V] f32 -> v_cat[B,2V]=[hi|lo], vT[V,B], vbd partials.
// blocks [4096,4608): w[V,H] f32 -> w_cat[V,2H], wT_cat[H,2V].
__global__ void prep_all_k(const float* __restrict__ v, u16* __restrict__ vcat,
                           u16* __restrict__ vT, float* __restrict__ vbd_p,
                           const float* __restrict__ w, u16* __restrict__ w_cat,
                           u16* __restrict__ wTc) {
  __shared__ u16 tile16[64][68];
  __shared__ float cs[16][64];
  __shared__ float tile32[64][65];
  const int bx = blockIdx.x;
  const int t = threadIdx.x;
  if (bx < 4096) {
    const int b0 = (bx & 127) << 6, c0 = (bx >> 7) << 6;
    const int rg = t >> 4;          // 0..15 row group
    const int cg = (t & 15) << 2;   // col *4
    float ca[4] = {0.f, 0.f, 0.f, 0.f};
#pragma unroll
    for (int i = 0; i < 4; ++i) {
      int r = rg + 16 * i;
      f32x4 x = *(const f32x4*)&v[(size_t)(b0 + r) * Vn + c0 + cg];
      u16x4 hi, lo;
#pragma unroll
      for (int j = 0; j < 4; ++j) {
        hi[j] = f2bf(x[j]);
        lo[j] = f2bf(x[j] - bf2f(hi[j]));
        tile16[r][cg + j] = hi[j];
        ca[j] += x[j];
      }
      *(u16x4*)&vcat[(size_t)(b0 + r) * (2 * Vn) + c0 + cg] = hi;
      *(u16x4*)&vcat[(size_t)(b0 + r) * (2 * Vn) + Vn + c0 + cg] = lo;
    }
#pragma unroll
    for (int j = 0; j < 4; ++j) cs[rg][cg + j] = ca[j];
    __syncthreads();
    if (t < 64) {
      float s = 0.f;
#pragma unroll
      for (int k = 0; k < 16; ++k) s += cs[k][t];
      vbd_p[(size_t)(bx & 127) * Vn + c0 + t] = s;   // [128][2048]
    }
#pragma unroll
    for (int s2 = 0; s2 < 2; ++s2) {
      int c = t >> 2;
      int seg = (t & 3) + 4 * s2;
      u16x8 pk;
#pragma unroll
      for (int i = 0; i < 8; ++i) pk[i] = tile16[seg * 8 + i][c];
      *(u16x8*)&vT[(size_t)(c0 + c) * Bn + b0 + seg * 8] = pk;
    }
  } else {
    const int wb = bx - 4096;
    const int v0 = (wb & 31) << 6, h0 = (wb >> 5) << 6;
    const int c = t & 63, r = t >> 6;
    for (int rr = r; rr < 64; rr += 4) {
      float x = w[(size_t)(v0 + rr) * Hn + h0 + c];
      tile32[rr][c] = x;
      u16 hi = f2bf(x), lo = f2bf(x - bf2f(hi));
      w_cat[(size_t)(v0 + rr) * (2 * Hn) + h0 + c]      = hi;
      w_cat[(size_t)(v0 + rr) * (2 * Hn) + Hn + h0 + c] = lo;
    }
    __syncthreads();
    for (int rr = r; rr < 64; rr += 4) {
      float x = tile32[c][rr];  // = w[v0+c][h0+rr]
      u16 hi = f2bf(x), lo = f2bf(x - bf2f(hi));
      size_t ro = (size_t)(h0 + rr) * (2 * Vn);
      wTc[ro + v0 + c]      = hi;
      wTc[ro + Vn + v0 + c] = lo;
    }
  }
}

// ---- sampling epilogue for split-K [B,H] pre-activations ----------------
// M==1: writes h_pred f32 / h_p bf16 / hbin bf16 / hT bf16 (u16), hbd colsums.
// M==5: writes h2T as u8 {0,1} (feeds i8 G6), hbm colsums.
template <int M>
__global__ void epi_h_k(const float* __restrict__ p0, const float* __restrict__ p1,
                        const float* __restrict__ bias, const float* __restrict__ uni,
                        float* __restrict__ f32out, u16* __restrict__ hp_out,
                        u16* __restrict__ hbin_out, u16* __restrict__ tout,
                        float* __restrict__ colp) {
  __shared__ u16 tile[64][68];
  __shared__ float cs[16][64];
  const int b0 = blockIdx.x * 64, c0 = blockIdx.y * 64;
  const int t = threadIdx.x;
  const int rg = t >> 4, cg = (t & 15) << 2;
  float ca[4] = {0.f, 0.f, 0.f, 0.f};
#pragma unroll
  for (int i = 0; i < 4; ++i) {
    int r = rg + 16 * i;
    size_t e = (size_t)(b0 + r) * Hn + c0 + cg;
    f32x4 a = *(const f32x4*)&p0[e];
    f32x4 b = *(const f32x4*)&p1[e];
    f32x4 uu = *(const f32x4*)&uni[e];
    f32x4 hpv;
    u16x4 hb16, qv;
#pragma unroll
    for (int j = 0; j < 4; ++j) {
      float hp = sigmoidf_(a[j] + b[j] + bias[c0 + cg + j]);
      u16 qb = (hp > uu[j]) ? (u16)0x3F80 : (u16)0;
      tile[r][cg + j] = qb;
      if constexpr (M == 1) {
        hpv[j] = hp; hb16[j] = f2bf(hp); qv[j] = qb;
        ca[j] += hp;
      } else {
        ca[j] += (qb ? 1.f : 0.f);
      }
    }
    if constexpr (M == 1) {
      *(f32x4*)&f32out[e] = hpv;        // h_prediction (overwrites p0 region)
      *(u16x4*)&hp_out[e] = hb16;
      *(u16x4*)&hbin_out[e] = qv;
    }
  }
#pragma unroll
  for (int j = 0; j < 4; ++j) cs[rg][cg + j] = ca[j];
  __syncthreads();
  if (t < 64) {
    float s = 0.f;
#pragma unroll
    for (int k = 0; k < 16; ++k) s += cs[k][t];
    colp[(size_t)blockIdx.x * Hn + c0 + t] = s;   // [128][1024]
  }
  if constexpr (M == 5) {
    u8* tout8 = (u8*)tout;
#pragma unroll
    for (int s2 = 0; s2 < 2; ++s2) {
      int c = t >> 2;
      int seg = (t & 3) + 4 * s2;
      u8x8 pk;
#pragma unroll
      for (int i = 0; i < 8; ++i) pk[i] = tile[seg * 8 + i][c] ? (u8)1 : (u8)0;
      *(u8x8*)&tout8[(size_t)(c0 + c) * Bn + b0 + seg * 8] = pk;
    }
  } else {
#pragma unroll
    for (int s2 = 0; s2 < 2; ++s2) {
      int c = t >> 2;
      int seg = (t & 3) + 4 * s2;
      u16x8 pk;
#pragma unroll
      for (int i = 0; i < 8; ++i) pk[i] = tile[seg * 8 + i][c];
      *(u16x8*)&tout[(size_t)(c0 + c) * Bn + b0 + seg * 8] = pk;
    }
  }
}

// ---------------- GEMM 256x256, BK=32, 8 waves, 2-phase counted pipeline --
// MODE 1: G1 split-K x2 partial (A remap [hi|hi|lo], B remap [hi|lo|hi]).
// MODE 4: G4 vk: A=hbin (dup), B=w_cat, K=2048 -> vk, vkT(u8), vbm (fused).
// MODE 5: G5 split-K x2 partial: A=vk (dup), B=wT_cat.
template <int MODE>
__global__ __launch_bounds__(512) void gemm256(
    const u16* __restrict__ A, int lda, const u16* __restrict__ Bm, int ldb, int K,
    const float* __restrict__ bias, const float* __restrict__ uni,
    const float* __restrict__ aux, float* __restrict__ f32out,
    u16* __restrict__ bfout, const u16* __restrict__ aux16,
    float* __restrict__ redp, u16* __restrict__ tout, float* __restrict__ colp) {
  constexpr bool TRANS = (MODE == 4);
  // As[4][256][32] at 0 (32768 u16), Bs[4][256][32] at 32768; 128 KB.
  // MODE4 epilogue ebuf [256][264] (67584 u16 = 132 KB) aliases everything.
  __shared__ __align__(16) u16 smem[TRANS ? 67584 : 65536];
  const int t = threadIdx.x;
  const int lane = t & 63, wave = t >> 6;                // 8 waves
  const int wr = (wave >> 2) << 7;                       // 0 / 128
  const int wc = (wave & 3) << 6;                        // 0/64/128/192
  const int bidx = blockIdx.x, bidy = blockIdx.y, bidz = blockIdx.z;
  const int bm = bidx << 8, bn = bidy << 8;
  int kbeg = 0;
  float* pout = f32out;
  if constexpr (MODE == 1 || MODE == 5) {
    kbeg = bidz * K;
    pout = (bidz == 0) ? f32out : redp;
  }
  f32x4 acc[8][4] = {};
  // staging (one gload = 512 thr x 16B = 128 rows x 64B): LDS row sr = t>>2,
  // granule t&3; fetch SWIZZLED global granule (t&3) ^ ((row>>1)&3) [r5 T2].
  const int sr = t >> 2;
  const int sc = (((t & 3) ^ ((t >> 3) & 3)) << 3);
  const u16* Ag  = A  + (size_t)(bm + sr) * lda + sc;
  const u16* Ag2 = Ag + (size_t)128 * lda;
  const u16* Bg  = Bm + (size_t)(bn + sr) * ldb + sc;
  const u16* Bg2 = Bg + (size_t)128 * ldb;
  const int fr = lane & 15, fg = lane >> 4;
  const int ga = ((fg ^ ((fr >> 1) & 3)) << 3);          // swizzled read granule

  auto acolf = [&](int k0) -> int {
    if constexpr (MODE == 1)      return (k0 < 2048) ? k0 : k0 - 2048;  // [hi|hi|lo]
    else if constexpr (MODE == 4) return k0 & 1023;
    else if constexpr (MODE == 5) return k0 & 2047;
    else                          return k0;
  };
  auto bcolf = [&](int k0) -> int {
    if constexpr (MODE == 1) return (k0 < 4096) ? k0 : k0 - 4096;       // [hi|lo|hi]
    else                     return k0;
  };
  auto stageA = [&](int kt) {
    const int k0 = kbeg + (kt << 5);
    const int acol = acolf(k0);
    u16* ad = smem + (kt & 3) * 8192 + wave * 512;       // wave-uniform base
    gload16(Ag + acol, ad);
    gload16(Ag2 + acol, ad + 4096);
  };
  auto stageB = [&](int kt) {
    const int k0 = kbeg + (kt << 5);
    const int bcol = bcolf(k0);
    u16* bd = smem + 32768 + (kt & 3) * 8192 + wave * 512;
    gload16(Bg + bcol, bd);
    gload16(Bg2 + bcol, bd + 4096);
  };
  // MODE 4 epilogue-tile L2 prefetch: one probe per 128B L2 line;
  // uni f32 [256][256] tile = 2048 lines = 4 chunks x 512 thr.
  auto pfl4 = [&](int ci) -> float {
    const int L = (ci << 9) + t;         // 0..2047
    return uni[(size_t)(bm + (L >> 3)) * Vn + bn + ((L & 7) << 5)];
  };

  // 2-phase-per-tile counted pipeline (depth-4 slabs, pb = kt&3):
  // steady outstanding at phase-B vmcnt = 12 -> vmcnt(8) guards tile kt+1.
  const int NT = K >> 5;
  const int pfbeg = NT - 8;
  stageA(0); stageB(0); stageA(1); stageB(1); stageA(2); stageB(2);
  asm volatile("s_waitcnt vmcnt(8)" ::: "memory");
  __builtin_amdgcn_s_barrier();
  asm volatile("" ::: "memory");
  s16x8 bf[4], af[4];
  for (int kt = 0; kt < NT; ++kt) {
    const int pb = kt & 3;
    const u16* Ab = smem + pb * 8192;
    const u16* Bb = smem + 32768 + pb * 8192;
    const bool st = (kt < NT - 3);
    // ---- phase A: reads + A-stage + barrier + MFMA lo ----
#pragma unroll
    for (int n = 0; n < 4; ++n)
      bf[n] = *(const s16x8*)&Bb[(wc + n * 16 + fr) * 32 + ga];
#pragma unroll
    for (int m = 0; m < 4; ++m)
      af[m] = *(const s16x8*)&Ab[(wr + m * 16 + fr) * 32 + ga];
    if (st) stageA(kt + 3);
    if constexpr (MODE == 4) {
      if (kt >= pfbeg && kt < pfbeg + 4) {
        float pfv = pfl4(kt - pfbeg);
        asm volatile("" :: "v"(pfv));
      }
    }
    __builtin_amdgcn_s_barrier();
    asm volatile("" ::: "memory");
    __builtin_amdgcn_s_setprio(1);
#pragma unroll
    for (int m = 0; m < 4; ++m)
#pragma unroll
      for (int n = 0; n < 4; ++n)
        acc[m][n] = __builtin_amdgcn_mfma_f32_16x16x32_bf16(af[m], bf[n], acc[m][n], 0, 0, 0);
    __builtin_amdgcn_s_setprio(0);
    // ---- phase B: reads + B-stage + vmcnt + barrier + MFMA hi ----
#pragma unroll
    for (int m = 0; m < 4; ++m)
      af[m] = *(const s16x8*)&Ab[(wr + (m + 4) * 16 + fr) * 32 + ga];
    if (st) stageB(kt + 3);
    if (kt < NT - 3) {
      asm volatile("s_waitcnt vmcnt(8)" ::: "memory");
    } else if (kt == NT - 3) {
      asm volatile("s_waitcnt vmcnt(4)" ::: "memory");
    } else if (kt == NT - 2) {
      asm volatile("s_waitcnt vmcnt(0)" ::: "memory");
    }
    __builtin_amdgcn_s_barrier();
    asm volatile("" ::: "memory");
    __builtin_amdgcn_s_setprio(1);
#pragma unroll
    for (int m = 0; m < 4; ++m)
#pragma unroll
      for (int n = 0; n < 4; ++n)
        acc[m + 4][n] = __builtin_amdgcn_mfma_f32_16x16x32_bf16(af[m], bf[n], acc[m + 4][n], 0, 0, 0);
    __builtin_amdgcn_s_setprio(0);
  }

  // ---- epilogue ----
  constexpr int NC = (MODE == 4) ? Vn : Hn;
  const int fq = lane >> 4;

  if constexpr (MODE == 1 || MODE == 5) {
#pragma unroll
    for (int m = 0; m < 8; ++m)
#pragma unroll
      for (int n = 0; n < 4; ++n)
#pragma unroll
        for (int j = 0; j < 4; ++j) {
          int rl = wr + m * 16 + fq * 4 + j;
          int cl = wc + n * 16 + fr;
          pout[(size_t)(bm + rl) * NC + bn + cl] = acc[m][n][j];
        }
  }

  if constexpr (MODE == 4) {
    __syncthreads();   // all waves done with dbuf before ebuf writes
    float bcol[4];
#pragma unroll
    for (int n = 0; n < 4; ++n) bcol[n] = bias[bn + wc + n * 16 + fr];
    const size_t ebase = (size_t)(bm + wr + fq * 4) * NC + (bn + wc + fr);
    float ux[8][4];
    auto ld4 = [&](int ci, float* dst) {
      size_t e0 = ebase + (size_t)((ci >> 2) << 4) * NC + ((ci & 3) << 4);
      dst[0] = uni[e0];          dst[1] = uni[e0 + NC];
      dst[2] = uni[e0 + 2 * NC]; dst[3] = uni[e0 + 3 * NC];
    };
#pragma unroll
    for (int ci = 0; ci < 8; ++ci) ld4(ci, ux[ci]);
#pragma unroll
    for (int m = 0; m < 8; ++m)
#pragma unroll
      for (int n = 0; n < 4; ++n)
#pragma unroll
        for (int j = 0; j < 4; ++j)
          acc[m][n][j] = sigmoidf_(acc[m][n][j] + bcol[n]);
    float csum[4] = {0.f, 0.f, 0.f, 0.f};
#pragma unroll
    for (int ci = 0; ci < 32; ++ci) {
      const int m = ci >> 2, n = ci & 3;
      const int rl = wr + m * 16 + fq * 4;
      const int cl = wc + n * 16 + fr;
#pragma unroll
      for (int j = 0; j < 4; ++j) {
        u16 qb = (acc[m][n][j] > ux[ci & 7][j]) ? (u16)0x3F80 : (u16)0;
        smem[(rl + j) * 264 + cl] = qb;          // ebuf (feeds vk AND vkT)
        csum[n] += (qb ? 1.f : 0.f);
      }
      if (ci < 24) ld4(ci + 8, ux[ci & 7]);
    }
    // vbm partials: lane covers 32 rows; xor16+xor32 reduces fq -> 128 rows
#pragma unroll
    for (int n = 0; n < 4; ++n) {
      float s = csum[n];
      s += __shfl_xor(s, 16);
      s += __shfl_xor(s, 32);
      if (fq == 0)
        colp[(size_t)(bidx * 2 + (wr >> 7)) * NC + (bn + wc + n * 16 + fr)] = s;
    }
    __syncthreads();   // ebuf fully written
    // vk row-major writeout: coalesced u16x8 from ebuf.
#pragma unroll
    for (int it = 0; it < 16; ++it) {
      int id = t + (it << 9);
      int r = id >> 5;                   // 0..255
      int c0 = (id & 31) << 3;           // 0..248
      u16x8 pk = *(const u16x8*)&smem[r * 264 + c0];
      *(u16x8*)&bfout[(size_t)(bm + r) * NC + bn + c0] = pk;
    }
    // vkT u8 writeout: thread owns (col c, 128-row half) -> 128B contiguous.
    {
      u8* tout8 = (u8*)tout;
      const int c = t & 255;
      const int half = t >> 8;           // 0..1
#pragma unroll
      for (int i8_ = 0; i8_ < 16; ++i8_) {
        u8x8 pk;
#pragma unroll
        for (int i2 = 0; i2 < 8; ++i2)
          pk[i2] = smem[(half * 128 + i8_ * 8 + i2) * 264 + c] ? (u8)1 : (u8)0;
        *(u8x8*)&tout8[(size_t)(bn + c) * Bn + bm + half * 128 + i8_ * 8] = pk;
      }
    }
  }
}

// ---------------- i8 GEMM for G6 (binary x binary, exact) -----------------
// A = vkT u8 [V,B], B = h2T u8 [H,B]; split-K x8 over B (z-slice XCD
// swizzle); NT=16 tiles of K=64 i8. mfma_i32_16x16x64_i8; i32 -> f32.
__global__ __launch_bounds__(512) void gemm_i8_k(
    const u8* __restrict__ A, const u8* __restrict__ Bm,
    float* __restrict__ out0, float* __restrict__ out4) {
  __shared__ __align__(16) u8 smem[131072];
  const int t = threadIdx.x;
  const int lane = t & 63, wave = t >> 6;
  const int wr = (wave >> 2) << 7;
  const int wc = (wave & 3) << 6;
  const int orig = blockIdx.x + (blockIdx.y << 3) + (blockIdx.z << 5);
  const int bidz = orig & 7;
  const int rr = orig >> 3;
  const int bidx = rr & 7, bidy = rr >> 3;
  const int bm = bidx << 8, bn = bidy << 8;
  const int kbeg = bidz << 10;           // 1024 u8 per z-slice
  float* pout = ((bidz < 4) ? out0 : out4) + (size_t)(bidz & 3) * VH;
  i32x4 acc[8][4] = {};
  const int sr = t >> 2;
  const int sc = (((t & 3) ^ ((t >> 3) & 3)) << 4);    // 16B granule (bytes)
  const u8* Ag  = A  + (size_t)(bm + sr) * Bn + sc;
  const u8* Ag2 = Ag + (size_t)128 * Bn;
  const u8* Bg  = Bm + (size_t)(bn + sr) * Bn + sc;
  const u8* Bg2 = Bg + (size_t)128 * Bn;
  const int fr = lane & 15, fg = lane >> 4;
  const int ga = ((fg ^ ((fr >> 1) & 3)) << 4);        // bytes

  auto stageA = [&](int kt) {
    u8* ad = smem + (kt & 3) * 16384 + wave * 1024;
    gload16(Ag + kbeg + (kt << 6), ad);
    gload16(Ag2 + kbeg + (kt << 6), ad + 8192);
  };
  auto stageB = [&](int kt) {
    u8* bd = smem + 65536 + (kt & 3) * 16384 + wave * 1024;
    gload16(Bg + kbeg + (kt << 6), bd);
    gload16(Bg2 + kbeg + (kt << 6), bd + 8192);
  };

  constexpr int NT = 16;
  stageA(0); stageB(0); stageA(1); stageB(1); stageA(2); stageB(2);
  asm volatile("s_waitcnt vmcnt(8)" ::: "memory");
  __builtin_amdgcn_s_barrier();
  asm volatile("" ::: "memory");
  i32x4 bf[4], af[4];
  for (int kt = 0; kt < NT; ++kt) {
    const u8* Ab = smem + (kt & 3) * 16384;
    const u8* Bb = smem + 65536 + (kt & 3) * 16384;
    const bool st = (kt < NT - 3);
    // phase A
#pragma unroll
    for (int n = 0; n < 4; ++n)
      bf[n] = *(const i32x4*)&Bb[(wc + n * 16 + fr) * 64 + ga];
#pragma unroll
    for (int m = 0; m < 4; ++m)
      af[m] = *(const i32x4*)&Ab[(wr + m * 16 + fr) * 64 + ga];
    if (st) stageA(kt + 3);
    __builtin_amdgcn_s_barrier();
    asm volatile("" ::: "memory");
    __builtin_amdgcn_s_setprio(1);
#pragma unroll
    for (int m = 0; m < 4; ++m)
#pragma unroll
      for (int n = 0; n < 4; ++n)
        acc[m][n] = __builtin_amdgcn_mfma_i32_16x16x64_i8(af[m], bf[n], acc[m][n], 0, 0, 0);
    __builtin_amdgcn_s_setprio(0);
    // phase B
#pragma unroll
    for (int m = 0; m < 4; ++m)
      af[m] = *(const i32x4*)&Ab[(wr + (m + 4) * 16 + fr) * 64 + ga];
    if (st) stageB(kt + 3);
    if (kt < NT - 3) {
      asm volatile("s_waitcnt vmcnt(8)" ::: "memory");
    } else if (kt == NT - 3) {
      asm volatile("s_waitcnt vmcnt(4)" ::: "memory");
    } else if (kt == NT - 2) {
      asm volatile("s_waitcnt vmcnt(0)" ::: "memory");
    }
    __builtin_amdgcn_s_barrier();
    asm volatile("" ::: "memory");
    __builtin_amdgcn_s_setprio(1);
#pragma unroll
    for (int m = 0; m < 4; ++m)
#pragma unroll
      for (int n = 0; n < 4; ++n)
        acc[m + 4][n] = __builtin_amdgcn_mfma_i32_16x16x64_i8(af[m], bf[n], acc[m + 4][n], 0, 0, 0);
    __builtin_amdgcn_s_setprio(0);
  }

  const int fq = lane >> 4;
#pragma unroll
  for (int m = 0; m < 8; ++m)
#pragma unroll
    for (int n = 0; n < 4; ++n)
#pragma unroll
      for (int j = 0; j < 4; ++j) {
        int rl = wr + m * 16 + fq * 4 + j;
        int cl = wc + n * 16 + fr;
        pout[(size_t)(bm + rl) * Hn + bn + cl] = (float)acc[m][n][j];
      }
}

// ---------------- merged G2+G3 (512 blocks, one launch) -------------------
// flat < 256:  G2 recon. A=h_p[B,H], B=w_cat hi, K=1024, NC=2048;
//              epilogue: sigmoid + |v_hi - vp| partial -> redp2[bidy*32+bidx].
// flat >= 256: G3 grad. A=vT+z*1024, B=hT+z*1024 (ld=Bn), K=1024, NC=1024;
//              z-slice XCD swizzle (flat%8 preserved: 256 == 0 mod 8).
__global__ __launch_bounds__(512) void g23_k(
    const u16* __restrict__ A2, const u16* __restrict__ B2,
    const u16* __restrict__ aux16, const float* __restrict__ bias2,
    float* __restrict__ redp2,
    const u16* __restrict__ A3, const u16* __restrict__ B3,
    float* __restrict__ out30, float* __restrict__ out34) {
  __shared__ __align__(16) u16 smem[65536];
  const int t = threadIdx.x;
  const int lane = t & 63, wave = t >> 6;
  const int wr = (wave >> 2) << 7;
  const int wc = (wave & 3) << 6;
  const int flat = blockIdx.x;
  const bool isG2 = (flat < 256);
  int bidx, bidy, bidz = 0;
  const u16 *Abase, *Bbase;
  int lda, ldb;
  if (isG2) {
    bidx = flat & 31; bidy = flat >> 5;
    Abase = A2; Bbase = B2; lda = Hn; ldb = 2 * Hn;
  } else {
    const int orig = flat - 256;
    bidz = orig & 7;
    const int rr = orig >> 3;          // 0..31 rank within XCD
    bidx = rr & 7; bidy = rr >> 3;
    Abase = A3 + (size_t)bidz * 1024;
    Bbase = B3 + (size_t)bidz * 1024;
    lda = Bn; ldb = Bn;
  }
  const int bm = bidx << 8, bn = bidy << 8;
  f32x4 acc[8][4] = {};
  const int sr = t >> 2;
  const int sc = (((t & 3) ^ ((t >> 3) & 3)) << 3);
  const u16* Ag  = Abase + (size_t)(bm + sr) * lda + sc;
  const u16* Ag2 = Ag + (size_t)128 * lda;
  const u16* Bg  = Bbase + (size_t)(bn + sr) * ldb + sc;
  const u16* Bg2 = Bg + (size_t)128 * ldb;
  const int fr = lane & 15, fg = lane >> 4;
  const int ga = ((fg ^ ((fr >> 1) & 3)) << 3);

  auto stageA = [&](int kt) {
    u16* ad = smem + (kt & 3) * 8192 + wave * 512;
    gload16(Ag + (kt << 5), ad);
    gload16(Ag2 + (kt << 5), ad + 4096);
  };
  auto stageB = [&](int kt) {
    u16* bd = smem + 32768 + (kt & 3) * 8192 + wave * 512;
    gload16(Bg + (kt << 5), bd);
    gload16(Bg2 + (kt << 5), bd + 4096);
  };
  auto pfl2 = [&](int ci) -> unsigned {
    const int L = (ci << 9) + t;         // 0..1023
    return (unsigned)aux16[(size_t)(bm + (L >> 2)) * 4096 + bn + ((L & 3) << 6)];
  };

  constexpr int NT = 32;
  stageA(0); stageB(0); stageA(1); stageB(1); stageA(2); stageB(2);
  asm volatile("s_waitcnt vmcnt(8)" ::: "memory");
  __builtin_amdgcn_s_barrier();
  asm volatile("" ::: "memory");
  s16x8 bf[4], af[4];
  for (int kt = 0; kt < NT; ++kt) {
    const int pb = kt & 3;
    const u16* Ab = smem + pb * 8192;
    const u16* Bb = smem + 32768 + pb * 8192;
    const bool st = (kt < NT - 3);
    // phase A
#pragma unroll
    for (int n = 0; n < 4; ++n)
      bf[n] = *(const s16x8*)&Bb[(wc + n * 16 + fr) * 32 + ga];
#pragma unroll
    for (int m = 0; m < 4; ++m)
      af[m] = *(const s16x8*)&Ab[(wr + m * 16 + fr) * 32 + ga];
    if (st) stageA(kt + 3);
    if (isG2 && kt >= NT - 8 && kt < NT - 6) {
      unsigned pfv = pfl2(kt - (NT - 8));
      asm volatile("" :: "v"(pfv));
    }
    __builtin_amdgcn_s_barrier();
    asm volatile("" ::: "memory");
    __builtin_amdgcn_s_setprio(1);
#pragma unroll
    for (int m = 0; m < 4; ++m)
#pragma unroll
      for (int n = 0; n < 4; ++n)
        acc[m][n] = __builtin_amdgcn_mfma_f32_16x16x32_bf16(af[m], bf[n], acc[m][n], 0, 0, 0);
    __builtin_amdgcn_s_setprio(0);
    // phase B
#pragma unroll
    for (int m = 0; m < 4; ++m)
      af[m] = *(const s16x8*)&Ab[(wr + (m + 4) * 16 + fr) * 32 + ga];
    if (st) stageB(kt + 3);
    if (kt < NT - 3) {
      asm volatile("s_waitcnt vmcnt(8)" ::: "memory");
    } else if (kt == NT - 3) {
      asm volatile("s_waitcnt vmcnt(4)" ::: "memory");
    } else if (kt == NT - 2) {
      asm volatile("s_waitcnt vmcnt(0)" ::: "memory");
    }
    __builtin_amdgcn_s_barrier();
    asm volatile("" ::: "memory");
    __builtin_amdgcn_s_setprio(1);
#pragma unroll
    for (int m = 0; m < 4; ++m)
#pragma unroll
      for (int n = 0; n < 4; ++n)
        acc[m + 4][n] = __builtin_amdgcn_mfma_f32_16x16x32_bf16(af[m], bf[n], acc[m + 4][n], 0, 0, 0);
    __builtin_amdgcn_s_setprio(0);
  }

  const int fq = lane >> 4;
  if (isG2) {
    // pipelined recon vs v_cat-hi (u16, stride 4096), depth-8 window (&7).
    float bcol[4];
#pragma unroll
    for (int n = 0; n < 4; ++n) bcol[n] = bias2[bn + wc + n * 16 + fr];
    const size_t ebase = (size_t)(bm + wr + fq * 4) * 4096 + (bn + wc + fr);
    float ax[8][4];
    auto ld4 = [&](int ci, float* dst) {
      size_t e0 = ebase + (size_t)((ci >> 2) << 4) * 4096 + ((ci & 3) << 4);
      dst[0] = bf2f(aux16[e0]);            dst[1] = bf2f(aux16[e0 + 4096]);
      dst[2] = bf2f(aux16[e0 + 2 * 4096]); dst[3] = bf2f(aux16[e0 + 3 * 4096]);
    };
#pragma unroll
    for (int ci = 0; ci < 8; ++ci) ld4(ci, ax[ci]);
#pragma unroll
    for (int m = 0; m < 8; ++m)
#pragma unroll
      for (int n = 0; n < 4; ++n)
#pragma unroll
        for (int j = 0; j < 4; ++j)
          acc[m][n][j] = sigmoidf_(acc[m][n][j] + bcol[n]);
    float lsum = 0.f;
#pragma unroll
    for (int ci = 0; ci < 32; ++ci) {
      const int m = ci >> 2, n = ci & 3;
#pragma unroll
      for (int j = 0; j < 4; ++j) lsum += fabsf(ax[ci & 7][j] - acc[m][n][j]);
      if (ci < 24) ld4(ci + 8, ax[ci & 7]);
    }
#pragma unroll
    for (int off = 32; off > 0; off >>= 1) lsum += __shfl_down(lsum, off);
    __syncthreads();
    float* redlds = (float*)smem;
    if (lane == 0) redlds[wave] = lsum;
    __syncthreads();
    if (t == 0) {
      float s = 0.f;
#pragma unroll
      for (int wv = 0; wv < 8; ++wv) s += redlds[wv];
      redp2[(size_t)bidy * 32 + bidx] = s;
    }
  } else {
    float* pout = ((bidz < 4) ? out30 : out34) + (size_t)(bidz & 3) * VH;
#pragma unroll
    for (int m = 0; m < 8; ++m)
#pragma unroll
      for (int n = 0; n < 4; ++n)
#pragma unroll
        for (int j = 0; j < 4; ++j) {
          int rl = wr + m * 16 + fq * 4 + j;
          int cl = wc + n * 16 + fr;
          pout[(size_t)(bm + rl) * Hn + bn + cl] = acc[m][n][j];
        }
  }
}

// out[i] = sum_{z<8} p[z][i]  (scalar stores: out base misaligned)
__global__ void reduce8_k(const float* __restrict__ p, float* __restrict__ out) {
  size_t e = ((size_t)blockIdx.x * 256 + threadIdx.x) * 4;
  f32x4 r = {};
#pragma unroll
  for (int z = 0; z < 8; ++z) r += *(const f32x4*)&p[(size_t)z * VH + e];
  out[e + 0] = r[0]; out[e + 1] = r[1]; out[e + 2] = r[2]; out[e + 3] = r[3];
}

// merged tail: blocks <2048 = reduce8s (w_grad = model partials - data grad),
// blocks >=2048 (8) = finalize (bias grads + recon scalar).
__global__ void tail_k(const float* __restrict__ pa, const float* __restrict__ pb,
                       const float* __restrict__ sums, float* __restrict__ out) {
  const int b = blockIdx.x;
  float* outw = out + OUT_WGRAD;
  if (b < 2048) {
    size_t e = ((size_t)b * 256 + threadIdx.x) * 4;
    f32x4 r = {};
#pragma unroll
    for (int z = 0; z < 4; ++z) r += *(const f32x4*)&pa[(size_t)z * VH + e];
#pragma unroll
    for (int z = 0; z < 4; ++z) r += *(const f32x4*)&pb[(size_t)z * VH + e];
    float s0 = outw[e + 0], s1 = outw[e + 1], s2 = outw[e + 2], s3 = outw[e + 3];
    outw[e + 0] = r[0] - s0; outw[e + 1] = r[1] - s1;
    outw[e + 2] = r[2] - s2; outw[e + 3] = r[3] - s3;
  } else {
    const int i = (b - 2048) * 256 + threadIdx.x;   // 0..2047
    const float* recon_p = sums;                 // 256
    const float* vbd = sums + 1024;              // 128 x 2048
    const float* hbd = vbd + 128 * 2048;         // 128 x 1024
    const float* vbm = hbd + 128 * 1024;         // 64 x 2048
    const float* hbm = vbm + 128 * 2048;         // 128 x 1024
    if (i < 2048) {
      float d = 0.f, m = 0.f;
      for (int k = 0; k < 128; ++k) d += vbd[k * 2048 + i];
      for (int k = 0; k < 64; ++k)  m += vbm[k * 2048 + i];
      out[OUT_VBG + i] = m - d;
    }
    if (i < 1024) {
      float d = 0.f, m = 0.f;
      for (int k = 0; k < 128; ++k) { d += hbd[k * 1024 + i]; m += hbm[k * 1024 + i]; }
      out[OUT_HBG + i] = m - d;
    }
    if (i == 0) {
      float s = 0.f;
      for (int k = 0; k < 256; ++k) s += recon_p[k];
      out[OUT_RECON] = s * (1.0f / 16777216.0f);  // /(B*V)
    }
  }
}

extern "C" void kernel_launch(void* const* d_in, const int* in_sizes, int n_in,
                              void* d_out, int out_size, void* d_ws, size_t ws_size,
                              hipStream_t stream) {
  (void)in_sizes; (void)n_in; (void)out_size;
  const float* v   = (const float*)d_in[0];
  const float* w   = (const float*)d_in[1];
  const float* vb  = (const float*)d_in[2];
  const float* hb  = (const float*)d_in[3];
  const float* u_h = (const float*)d_in[4];
  const float* u_v = (const float*)d_in[5];
  float* out = (float*)d_out;
  char* ws = (char*)d_ws;
  if (ws_size < 204734464ULL) return;

  float* sums    = (float*)ws;               // 3.25 MiB region
  float* recon_p = sums;                     // 256
  float* vbd_p   = sums + 1024;              // 128*2048
  float* hbd_p   = vbd_p + 128 * 2048;       // 128*1024
  float* vbm_p   = hbd_p + 128 * 1024;       // 64*2048
  float* hbm_p   = vbm_p + 128 * 2048;       // 128*1024
  char* p = ws + 3407872;
  u16* v_cat  = (u16*)p;  p += (size_t)Bn * 2 * Vn * 2;   // 64 MiB [B,2V]
  u16* wT_cat = (u16*)p;  p += (size_t)Hn * 2 * Vn * 2;   // 8 MiB [H,2V]
  u16* w_cat  = (u16*)p;  p += (size_t)Vn * 2 * Hn * 2;   // 8 MiB [V,2H]
  u16* h_p    = (u16*)p;  p += BH * 2;                    // 16 MiB [B,H]
  u16* hbin   = (u16*)p;  p += BH * 2;                    // 16 MiB [B,H]
  u16* vT     = (u16*)p;  p += (size_t)Vn * Bn * 2;       // 32 MiB [V,B]
  u16* hT     = (u16*)p;  p += (size_t)Hn * Bn * 2;       // 16 MiB [H,B]
  float* big  = (float*)p;                                // 32 MiB time-shared
  u16* vk   = v_cat;            // v_cat dead after g23 (G3 partials overwrite)
  u8*  vkT8 = (u8*)vT;          // vT dead after g23; u8 vkT (16 MiB used)
  u8*  h2T8 = (u8*)hT;          // hT dead after g23; u8 h2T (8 MiB used)
  float* vcat_f = (float*)v_cat;   // 64 MiB: G3's 8 partials
  float* hpbuf  = (float*)h_p;     // h_p+hbin region (32 MiB) as f32 partials
  float* outW   = out + OUT_WGRAD;

  prep_all_k<<<4608, 256, 0, stream>>>(v, v_cat, vT, vbd_p, w, w_cat, wT_cat);
  // G1a: split-K x2 partials (z0 -> out[0..BH) scratch, z1 -> big)
  gemm256<1><<<dim3(32, 4, 2), 512, 0, stream>>>(
      v_cat, 2 * Vn, wT_cat, 2 * Vn, 3072, nullptr, nullptr, nullptr,
      out, nullptr, nullptr, big, nullptr, nullptr);
  // epi: h_pred / h_p / hbin / hT / hbd
  epi_h_k<1><<<dim3(128, 16), 256, 0, stream>>>(
      out, big, hb, u_h, out, h_p, hbin, hT, hbd_p);
  // merged G2 (recon) + G3 (w_data_grad partials): 512 blocks, one launch
  g23_k<<<512, 512, 0, stream>>>(
      h_p, w_cat, v_cat, vb, recon_p,
      vT, hT, vcat_f, vcat_f + 4 * VH);
  reduce8_k<<<2048, 256, 0, stream>>>(vcat_f, outW);   // outW = data-grad sum
  // G4: vk/vkT(u8) + vbm partials (fused sample+transpose epilogue)
  gemm256<4><<<dim3(32, 8), 512, 0, stream>>>(
      hbin, Hn, w_cat, 2 * Hn, 2 * Hn, vb, u_v, nullptr,
      nullptr, vk, nullptr, nullptr, (u16*)vkT8, vbm_p);
  // G5a: split-K x2 partials (z0 -> hpbuf, z1 -> big); h_p/hbin dead now
  gemm256<5><<<dim3(32, 4, 2), 512, 0, stream>>>(
      vk, Vn, wT_cat, 2 * Vn, 2048, nullptr, nullptr, nullptr,
      hpbuf, nullptr, nullptr, big, nullptr, nullptr);
  // epi: h2T (u8) + hbm
  epi_h_k<5><<<dim3(128, 16), 256, 0, stream>>>(
      hpbuf, big, hb, u_h + BH, nullptr, nullptr, nullptr, (u16*)h2T8, hbm_p);
  // G6: w_model_grad partials via i8 MFMA (exact; split-K x8)
  gemm_i8_k<<<dim3(8, 4, 8), 512, 0, stream>>>(vkT8, h2T8, hpbuf, big);
  // merged reduce8s + finalize
  tail_k<<<2056, 256, 0, stream>>>(hpbuf, big, sums, out);
}

// Round 15
// 479.263 us; speedup vs baseline: 1.0825x; 1.0099x over previous
//
#include <hip/hip_runtime.h>

// RBM CD-1 step on MI355X — round 23.
// = round-20/22 kernel (verified 479.7us best) + ONE concurrency seam:
// reduce8 and G4 are dependency-free (both need only g23+epi1 outputs) but
// serialized because vk aliased the v_cat region holding G3 partials.
// Fix: vk -> big (32MB, dead between epi1 and G5a), then merge into one
// launch g4red_k: blocks [0,1024) = reduce8 (512thr), [1024,1280) = the
// verbatim MODE-4 body (flat-1024 -> bidx/bidy; offset 1024%8==0 keeps XCD
// parity). reduce8's ~13us + a launch gap hide under G4's ramp.
// Ripple (liveness-checked): G5a A=big, z1 partials -> vcat_f+4VH (free
// after reduce8, which completes in the prior launch); epi5 p1 likewise;
// G6 z>=4 -> big (vk dead after G5a). No numerics change anywhere.

typedef unsigned short u16;
typedef unsigned char u8;
typedef short s16x8 __attribute__((ext_vector_type(8)));
typedef float f32x4 __attribute__((ext_vector_type(4)));
typedef int i32x4 __attribute__((ext_vector_type(4)));
typedef u16 u16x4 __attribute__((ext_vector_type(4)));
typedef u16 u16x8 __attribute__((ext_vector_type(8)));
typedef u8 u8x8 __attribute__((ext_vector_type(8)));

constexpr int Bn = 8192, Vn = 2048, Hn = 1024;
constexpr size_t VH = (size_t)Vn * Hn;
constexpr size_t BH = (size_t)Bn * Hn;
constexpr size_t OUT_RECON = BH;                        // 8388608
constexpr size_t OUT_WGRAD = OUT_RECON + 1;             // 8388609
constexpr size_t OUT_VBG   = OUT_WGRAD + VH;            // 10485761
constexpr size_t OUT_HBG   = OUT_VBG + Vn;              // 10487809

__device__ __forceinline__ u16 f2bf(float x) {
  union { float f; unsigned u; } a; a.f = x;
  unsigned r = a.u + 0x7FFFu + ((a.u >> 16) & 1u);   // RNE
  return (u16)(r >> 16);
}
__device__ __forceinline__ float bf2f(u16 h) {
  union { unsigned u; float f; } a; a.u = ((unsigned)h) << 16;
  return a.f;
}
__device__ __forceinline__ float sigmoidf_(float x) {
  return 1.0f / (1.0f + __expf(-x));
}

using gptr_t = const unsigned int __attribute__((address_space(1)))*;
using lptr_t = unsigned int __attribute__((address_space(3)))*;

__device__ __forceinline__ void gload16(const void* g, void* l) {
  __builtin_amdgcn_global_load_lds((gptr_t)(unsigned long long)g,
                                   (lptr_t)(unsigned long long)l, 16, 0, 0);
}

// ---------------- merged prep kernel ----------------
// blocks [0,4096): v[B,V] f32 -> v_cat[B,2V]=[hi|lo], vT[V,B], vbd partials.
// blocks [4096,4608): w[V,H] f32 -> w_cat[V,2H], wT_cat[H,2V].
__global__ void prep_all_k(const float* __restrict__ v, u16* __restrict__ vcat,
                           u16* __restrict__ vT, float* __restrict__ vbd_p,
                           const float* __restrict__ w, u16* __restrict__ w_cat,
                           u16* __restrict__ wTc) {
  __shared__ u16 tile16[64][68];
  __shared__ float cs[16][64];
  __shared__ float tile32[64][65];
  const int bx = blockIdx.x;
  const int t = threadIdx.x;
  if (bx < 4096) {
    const int b0 = (bx & 127) << 6, c0 = (bx >> 7) << 6;
    const int rg = t >> 4;          // 0..15 row group
    const int cg = (t & 15) << 2;   // col *4
    float ca[4] = {0.f, 0.f, 0.f, 0.f};
#pragma unroll
    for (int i = 0; i < 4; ++i) {
      int r = rg + 16 * i;
      f32x4 x = *(const f32x4*)&v[(size_t)(b0 + r) * Vn + c0 + cg];
      u16x4 hi, lo;
#pragma unroll
      for (int j = 0; j < 4; ++j) {
        hi[j] = f2bf(x[j]);
        lo[j] = f2bf(x[j] - bf2f(hi[j]));
        tile16[r][cg + j] = hi[j];
        ca[j] += x[j];
      }
      *(u16x4*)&vcat[(size_t)(b0 + r) * (2 * Vn) + c0 + cg] = hi;
      *(u16x4*)&vcat[(size_t)(b0 + r) * (2 * Vn) + Vn + c0 + cg] = lo;
    }
#pragma unroll
    for (int j = 0; j < 4; ++j) cs[rg][cg + j] = ca[j];
    __syncthreads();
    if (t < 64) {
      float s = 0.f;
#pragma unroll
      for (int k = 0; k < 16; ++k) s += cs[k][t];
      vbd_p[(size_t)(bx & 127) * Vn + c0 + t] = s;   // [128][2048]
    }
#pragma unroll
    for (int s2 = 0; s2 < 2; ++s2) {
      int c = t >> 2;
      int seg = (t & 3) + 4 * s2;
      u16x8 pk;
#pragma unroll
      for (int i = 0; i < 8; ++i) pk[i] = tile16[seg * 8 + i][c];
      *(u16x8*)&vT[(size_t)(c0 + c) * Bn + b0 + seg * 8] = pk;
    }
  } else {
    const int wb = bx - 4096;
    const int v0 = (wb & 31) << 6, h0 = (wb >> 5) << 6;
    const int c = t & 63, r = t >> 6;
    for (int rr = r; rr < 64; rr += 4) {
      float x = w[(size_t)(v0 + rr) * Hn + h0 + c];
      tile32[rr][c] = x;
      u16 hi = f2bf(x), lo = f2bf(x - bf2f(hi));
      w_cat[(size_t)(v0 + rr) * (2 * Hn) + h0 + c]      = hi;
      w_cat[(size_t)(v0 + rr) * (2 * Hn) + Hn + h0 + c] = lo;
    }
    __syncthreads();
    for (int rr = r; rr < 64; rr += 4) {
      float x = tile32[c][rr];  // = w[v0+c][h0+rr]
      u16 hi = f2bf(x), lo = f2bf(x - bf2f(hi));
      size_t ro = (size_t)(h0 + rr) * (2 * Vn);
      wTc[ro + v0 + c]      = hi;
      wTc[ro + Vn + v0 + c] = lo;
    }
  }
}

// ---- sampling epilogue for split-K [B,H] pre-activations ----------------
// M==1: writes h_pred f32 / h_p bf16 / hbin bf16 / hT bf16 (u16), hbd colsums.
// M==5: writes h2T as u8 {0,1} (feeds i8 G6), hbm colsums.
template <int M>
__global__ void epi_h_k(const float* __restrict__ p0, const float* __restrict__ p1,
                        const float* __restrict__ bias, const float* __restrict__ uni,
                        float* __restrict__ f32out, u16* __restrict__ hp_out,
                        u16* __restrict__ hbin_out, u16* __restrict__ tout,
                        float* __restrict__ colp) {
  __shared__ u16 tile[64][68];
  __shared__ float cs[16][64];
  const int b0 = blockIdx.x * 64, c0 = blockIdx.y * 64;
  const int t = threadIdx.x;
  const int rg = t >> 4, cg = (t & 15) << 2;
  float ca[4] = {0.f, 0.f, 0.f, 0.f};
#pragma unroll
  for (int i = 0; i < 4; ++i) {
    int r = rg + 16 * i;
    size_t e = (size_t)(b0 + r) * Hn + c0 + cg;
    f32x4 a = *(const f32x4*)&p0[e];
    f32x4 b = *(const f32x4*)&p1[e];
    f32x4 uu = *(const f32x4*)&uni[e];
    f32x4 hpv;
    u16x4 hb16, qv;
#pragma unroll
    for (int j = 0; j < 4; ++j) {
      float hp = sigmoidf_(a[j] + b[j] + bias[c0 + cg + j]);
      u16 qb = (hp > uu[j]) ? (u16)0x3F80 : (u16)0;
      tile[r][cg + j] = qb;
      if constexpr (M == 1) {
        hpv[j] = hp; hb16[j] = f2bf(hp); qv[j] = qb;
        ca[j] += hp;
      } else {
        ca[j] += (qb ? 1.f : 0.f);
      }
    }
    if constexpr (M == 1) {
      *(f32x4*)&f32out[e] = hpv;        // h_prediction (overwrites p0 region)
      *(u16x4*)&hp_out[e] = hb16;
      *(u16x4*)&hbin_out[e] = qv;
    }
  }
#pragma unroll
  for (int j = 0; j < 4; ++j) cs[rg][cg + j] = ca[j];
  __syncthreads();
  if (t < 64) {
    float s = 0.f;
#pragma unroll
    for (int k = 0; k < 16; ++k) s += cs[k][t];
    colp[(size_t)blockIdx.x * Hn + c0 + t] = s;   // [128][1024]
  }
  if constexpr (M == 5) {
    u8* tout8 = (u8*)tout;
#pragma unroll
    for (int s2 = 0; s2 < 2; ++s2) {
      int c = t >> 2;
      int seg = (t & 3) + 4 * s2;
      u8x8 pk;
#pragma unroll
      for (int i = 0; i < 8; ++i) pk[i] = tile[seg * 8 + i][c] ? (u8)1 : (u8)0;
      *(u8x8*)&tout8[(size_t)(c0 + c) * Bn + b0 + seg * 8] = pk;
    }
  } else {
#pragma unroll
    for (int s2 = 0; s2 < 2; ++s2) {
      int c = t >> 2;
      int seg = (t & 3) + 4 * s2;
      u16x8 pk;
#pragma unroll
      for (int i = 0; i < 8; ++i) pk[i] = tile[seg * 8 + i][c];
      *(u16x8*)&tout[(size_t)(c0 + c) * Bn + b0 + seg * 8] = pk;
    }
  }
}

// ---------------- GEMM 256x256, BK=32, 8 waves, 2-phase counted pipeline --
// MODE 1: G1 split-K x2 partial (A remap [hi|hi|lo], B remap [hi|lo|hi]).
// MODE 5: G5 split-K x2 partial: A=vk (dup), B=wT_cat.
template <int MODE>
__global__ __launch_bounds__(512) void gemm256(
    const u16* __restrict__ A, int lda, const u16* __restrict__ Bm, int ldb, int K,
    float* __restrict__ f32out, float* __restrict__ redp) {
  __shared__ __align__(16) u16 smem[65536];
  const int t = threadIdx.x;
  const int lane = t & 63, wave = t >> 6;                // 8 waves
  const int wr = (wave >> 2) << 7;                       // 0 / 128
  const int wc = (wave & 3) << 6;                        // 0/64/128/192
  const int bidx = blockIdx.x, bidy = blockIdx.y, bidz = blockIdx.z;
  const int bm = bidx << 8, bn = bidy << 8;
  const int kbeg = bidz * K;
  float* pout = (bidz == 0) ? f32out : redp;
  f32x4 acc[8][4] = {};
  const int sr = t >> 2;
  const int sc = (((t & 3) ^ ((t >> 3) & 3)) << 3);
  const u16* Ag  = A  + (size_t)(bm + sr) * lda + sc;
  const u16* Ag2 = Ag + (size_t)128 * lda;
  const u16* Bg  = Bm + (size_t)(bn + sr) * ldb + sc;
  const u16* Bg2 = Bg + (size_t)128 * ldb;
  const int fr = lane & 15, fg = lane >> 4;
  const int ga = ((fg ^ ((fr >> 1) & 3)) << 3);          // swizzled read granule

  auto acolf = [&](int k0) -> int {
    if constexpr (MODE == 1) return (k0 < 2048) ? k0 : k0 - 2048;  // [hi|hi|lo]
    else                     return k0 & 2047;                      // MODE 5 (vk dup)
  };
  auto bcolf = [&](int k0) -> int {
    if constexpr (MODE == 1) return (k0 < 4096) ? k0 : k0 - 4096;  // [hi|lo|hi]
    else                     return k0;
  };
  auto stageA = [&](int kt) {
    const int k0 = kbeg + (kt << 5);
    const int acol = acolf(k0);
    u16* ad = smem + (kt & 3) * 8192 + wave * 512;       // wave-uniform base
    gload16(Ag + acol, ad);
    gload16(Ag2 + acol, ad + 4096);
  };
  auto stageB = [&](int kt) {
    const int k0 = kbeg + (kt << 5);
    const int bcol = bcolf(k0);
    u16* bd = smem + 32768 + (kt & 3) * 8192 + wave * 512;
    gload16(Bg + bcol, bd);
    gload16(Bg2 + bcol, bd + 4096);
  };

  const int NT = K >> 5;
  stageA(0); stageB(0); stageA(1); stageB(1); stageA(2); stageB(2);
  asm volatile("s_waitcnt vmcnt(8)" ::: "memory");
  __builtin_amdgcn_s_barrier();
  asm volatile("" ::: "memory");
  s16x8 bf[4], af[4];
  for (int kt = 0; kt < NT; ++kt) {
    const int pb = kt & 3;
    const u16* Ab = smem + pb * 8192;
    const u16* Bb = smem + 32768 + pb * 8192;
    const bool st = (kt < NT - 3);
    // phase A
#pragma unroll
    for (int n = 0; n < 4; ++n)
      bf[n] = *(const s16x8*)&Bb[(wc + n * 16 + fr) * 32 + ga];
#pragma unroll
    for (int m = 0; m < 4; ++m)
      af[m] = *(const s16x8*)&Ab[(wr + m * 16 + fr) * 32 + ga];
    if (st) stageA(kt + 3);
    __builtin_amdgcn_s_barrier();
    asm volatile("" ::: "memory");
    __builtin_amdgcn_s_setprio(1);
#pragma unroll
    for (int m = 0; m < 4; ++m)
#pragma unroll
      for (int n = 0; n < 4; ++n)
        acc[m][n] = __builtin_amdgcn_mfma_f32_16x16x32_bf16(af[m], bf[n], acc[m][n], 0, 0, 0);
    __builtin_amdgcn_s_setprio(0);
    // phase B
#pragma unroll
    for (int m = 0; m < 4; ++m)
      af[m] = *(const s16x8*)&Ab[(wr + (m + 4) * 16 + fr) * 32 + ga];
    if (st) stageB(kt + 3);
    if (kt < NT - 3) {
      asm volatile("s_waitcnt vmcnt(8)" ::: "memory");
    } else if (kt == NT - 3) {
      asm volatile("s_waitcnt vmcnt(4)" ::: "memory");
    } else if (kt == NT - 2) {
      asm volatile("s_waitcnt vmcnt(0)" ::: "memory");
    }
    __builtin_amdgcn_s_barrier();
    asm volatile("" ::: "memory");
    __builtin_amdgcn_s_setprio(1);
#pragma unroll
    for (int m = 0; m < 4; ++m)
#pragma unroll
      for (int n = 0; n < 4; ++n)
        acc[m + 4][n] = __builtin_amdgcn_mfma_f32_16x16x32_bf16(af[m], bf[n], acc[m + 4][n], 0, 0, 0);
    __builtin_amdgcn_s_setprio(0);
  }

  const int fq = lane >> 4;
#pragma unroll
  for (int m = 0; m < 8; ++m)
#pragma unroll
    for (int n = 0; n < 4; ++n)
#pragma unroll
      for (int j = 0; j < 4; ++j) {
        int rl = wr + m * 16 + fq * 4 + j;
        int cl = wc + n * 16 + fr;
        pout[(size_t)(bm + rl) * Hn + bn + cl] = acc[m][n][j];
      }
}

// ------- merged reduce8 + G4 (1280 blocks, 512 thr) -----------------------
// blocks [0,1024): reduce8 — out[i] = sum_{z<8} rsrc[z][i] (f32x4 per thr).
// blocks [1024,1280): G4 vk GEMM — A=hbin[B,H] (dup z), B=w_cat[V,2H],
//   K=2048 -> sample -> vk(bf16, ->big) / vkT(u8) / vbm colsums. Verbatim
//   r20 MODE-4 body; bidx=orig&31, bidy=orig>>5 (offset 1024%8==0 keeps XCD).
__global__ __launch_bounds__(512) void g4red_k(
    const float* __restrict__ rsrc, float* __restrict__ rout,
    const u16* __restrict__ A, const u16* __restrict__ Bm,
    const float* __restrict__ bias, const float* __restrict__ uni,
    u16* __restrict__ bfout, u16* __restrict__ tout, float* __restrict__ colp) {
  __shared__ __align__(16) u16 smem[67584];
  const int t = threadIdx.x;
  if (blockIdx.x < 1024) {
    size_t e = ((size_t)blockIdx.x * 512 + t) * 4;
    f32x4 r = {};
#pragma unroll
    for (int z = 0; z < 8; ++z) r += *(const f32x4*)&rsrc[(size_t)z * VH + e];
    rout[e + 0] = r[0]; rout[e + 1] = r[1];
    rout[e + 2] = r[2]; rout[e + 3] = r[3];
    return;
  }
  const int orig = blockIdx.x - 1024;
  const int bidx = orig & 31, bidy = orig >> 5;
  const int lane = t & 63, wave = t >> 6;
  const int wr = (wave >> 2) << 7;
  const int wc = (wave & 3) << 6;
  const int bm = bidx << 8, bn = bidy << 8;
  constexpr int NC = Vn;
  constexpr int K = 2048;
  constexpr int lda = Hn, ldb = 2 * Hn;
  f32x4 acc[8][4] = {};
  const int sr = t >> 2;
  const int sc = (((t & 3) ^ ((t >> 3) & 3)) << 3);
  const u16* Ag  = A  + (size_t)(bm + sr) * lda + sc;
  const u16* Ag2 = Ag + (size_t)128 * lda;
  const u16* Bg  = Bm + (size_t)(bn + sr) * ldb + sc;
  const u16* Bg2 = Bg + (size_t)128 * ldb;
  const int fr = lane & 15, fg = lane >> 4;
  const int ga = ((fg ^ ((fr >> 1) & 3)) << 3);

  auto stageA = [&](int kt) {
    const int acol = (kt << 5) & 1023;                   // hbin dup over z
    u16* ad = smem + (kt & 3) * 8192 + wave * 512;
    gload16(Ag + acol, ad);
    gload16(Ag2 + acol, ad + 4096);
  };
  auto stageB = [&](int kt) {
    const int bcol = kt << 5;
    u16* bd = smem + 32768 + (kt & 3) * 8192 + wave * 512;
    gload16(Bg + bcol, bd);
    gload16(Bg2 + bcol, bd + 4096);
  };
  auto pfl4 = [&](int ci) -> float {
    const int L = (ci << 9) + t;         // 0..2047
    return uni[(size_t)(bm + (L >> 3)) * Vn + bn + ((L & 7) << 5)];
  };

  const int NT = K >> 5;
  const int pfbeg = NT - 8;
  stageA(0); stageB(0); stageA(1); stageB(1); stageA(2); stageB(2);
  asm volatile("s_waitcnt vmcnt(8)" ::: "memory");
  __builtin_amdgcn_s_barrier();
  asm volatile("" ::: "memory");
  s16x8 bf[4], af[4];
  for (int kt = 0; kt < NT; ++kt) {
    const int pb = kt & 3;
    const u16* Ab = smem + pb * 8192;
    const u16* Bb = smem + 32768 + pb * 8192;
    const bool st = (kt < NT - 3);
    // phase A
#pragma unroll
    for (int n = 0; n < 4; ++n)
      bf[n] = *(const s16x8*)&Bb[(wc + n * 16 + fr) * 32 + ga];
#pragma unroll
    for (int m = 0; m < 4; ++m)
      af[m] = *(const s16x8*)&Ab[(wr + m * 16 + fr) * 32 + ga];
    if (st) stageA(kt + 3);
    if (kt >= pfbeg && kt < pfbeg + 4) {
      float pfv = pfl4(kt - pfbeg);
      asm volatile("" :: "v"(pfv));
    }
    __builtin_amdgcn_s_barrier();
    asm volatile("" ::: "memory");
    __builtin_amdgcn_s_setprio(1);
#pragma unroll
    for (int m = 0; m < 4; ++m)
#pragma unroll
      for (int n = 0; n < 4; ++n)
        acc[m][n] = __builtin_amdgcn_mfma_f32_16x16x32_bf16(af[m], bf[n], acc[m][n], 0, 0, 0);
    __builtin_amdgcn_s_setprio(0);
    // phase B
#pragma unroll
    for (int m = 0; m < 4; ++m)
      af[m] = *(const s16x8*)&Ab[(wr + (m + 4) * 16 + fr) * 32 + ga];
    if (st) stageB(kt + 3);
    if (kt < NT - 3) {
      asm volatile("s_waitcnt vmcnt(8)" ::: "memory");
    } else if (kt == NT - 3) {
      asm volatile("s_waitcnt vmcnt(4)" ::: "memory");
    } else if (kt == NT - 2) {
      asm volatile("s_waitcnt vmcnt(0)" ::: "memory");
    }
    __builtin_amdgcn_s_barrier();
    asm volatile("" ::: "memory");
    __builtin_amdgcn_s_setprio(1);
#pragma unroll
    for (int m = 0; m < 4; ++m)
#pragma unroll
      for (int n = 0; n < 4; ++n)
        acc[m + 4][n] = __builtin_amdgcn_mfma_f32_16x16x32_bf16(af[m], bf[n], acc[m + 4][n], 0, 0, 0);
    __builtin_amdgcn_s_setprio(0);
  }

  const int fq = lane >> 4;
  __syncthreads();   // all waves done with dbuf before ebuf writes
  float bcol[4];
#pragma unroll
  for (int n = 0; n < 4; ++n) bcol[n] = bias[bn + wc + n * 16 + fr];
  const size_t ebase = (size_t)(bm + wr + fq * 4) * NC + (bn + wc + fr);
  float ux[8][4];
  auto ld4 = [&](int ci, float* dst) {
    size_t e0 = ebase + (size_t)((ci >> 2) << 4) * NC + ((ci & 3) << 4);
    dst[0] = uni[e0];          dst[1] = uni[e0 + NC];
    dst[2] = uni[e0 + 2 * NC]; dst[3] = uni[e0 + 3 * NC];
  };
#pragma unroll
  for (int ci = 0; ci < 8; ++ci) ld4(ci, ux[ci]);
#pragma unroll
  for (int m = 0; m < 8; ++m)
#pragma unroll
    for (int n = 0; n < 4; ++n)
#pragma unroll
      for (int j = 0; j < 4; ++j)
        acc[m][n][j] = sigmoidf_(acc[m][n][j] + bcol[n]);
  float csum[4] = {0.f, 0.f, 0.f, 0.f};
#pragma unroll
  for (int ci = 0; ci < 32; ++ci) {
    const int m = ci >> 2, n = ci & 3;
    const int rl = wr + m * 16 + fq * 4;
    const int cl = wc + n * 16 + fr;
#pragma unroll
    for (int j = 0; j < 4; ++j) {
      u16 qb = (acc[m][n][j] > ux[ci & 7][j]) ? (u16)0x3F80 : (u16)0;
      smem[(rl + j) * 264 + cl] = qb;          // ebuf (feeds vk AND vkT)
      csum[n] += (qb ? 1.f : 0.f);
    }
    if (ci < 24) ld4(ci + 8, ux[ci & 7]);
  }
  // vbm partials
#pragma unroll
  for (int n = 0; n < 4; ++n) {
    float s = csum[n];
    s += __shfl_xor(s, 16);
    s += __shfl_xor(s, 32);
    if (fq == 0)
      colp[(size_t)(bidx * 2 + (wr >> 7)) * NC + (bn + wc + n * 16 + fr)] = s;
  }
  __syncthreads();   // ebuf fully written
  // vk row-major writeout: coalesced u16x8 from ebuf.
#pragma unroll
  for (int it = 0; it < 16; ++it) {
    int id = t + (it << 9);
    int r = id >> 5;                   // 0..255
    int c0 = (id & 31) << 3;           // 0..248
    u16x8 pk = *(const u16x8*)&smem[r * 264 + c0];
    *(u16x8*)&bfout[(size_t)(bm + r) * NC + bn + c0] = pk;
  }
  // vkT u8 writeout: thread owns (col c, 128-row half) -> 128B contiguous.
  {
    u8* tout8 = (u8*)tout;
    const int c = t & 255;
    const int half = t >> 8;           // 0..1
#pragma unroll
    for (int i8_ = 0; i8_ < 16; ++i8_) {
      u8x8 pk;
#pragma unroll
      for (int i2 = 0; i2 < 8; ++i2)
        pk[i2] = smem[(half * 128 + i8_ * 8 + i2) * 264 + c] ? (u8)1 : (u8)0;
      *(u8x8*)&tout8[(size_t)(bn + c) * Bn + bm + half * 128 + i8_ * 8] = pk;
    }
  }
}

// ---------------- i8 GEMM for G6 (binary x binary, exact) -----------------
__global__ __launch_bounds__(512) void gemm_i8_k(
    const u8* __restrict__ A, const u8* __restrict__ Bm,
    float* __restrict__ out0, float* __restrict__ out4) {
  __shared__ __align__(16) u8 smem[131072];
  const int t = threadIdx.x;
  const int lane = t & 63, wave = t >> 6;
  const int wr = (wave >> 2) << 7;
  const int wc = (wave & 3) << 6;
  const int orig = blockIdx.x + (blockIdx.y << 3) + (blockIdx.z << 5);
  const int bidz = orig & 7;
  const int rr = orig >> 3;
  const int bidx = rr & 7, bidy = rr >> 3;
  const int bm = bidx << 8, bn = bidy << 8;
  const int kbeg = bidz << 10;           // 1024 u8 per z-slice
  float* pout = ((bidz < 4) ? out0 : out4) + (size_t)(bidz & 3) * VH;
  i32x4 acc[8][4] = {};
  const int sr = t >> 2;
  const int sc = (((t & 3) ^ ((t >> 3) & 3)) << 4);    // 16B granule (bytes)
  const u8* Ag  = A  + (size_t)(bm + sr) * Bn + sc;
  const u8* Ag2 = Ag + (size_t)128 * Bn;
  const u8* Bg  = Bm + (size_t)(bn + sr) * Bn + sc;
  const u8* Bg2 = Bg + (size_t)128 * Bn;
  const int fr = lane & 15, fg = lane >> 4;
  const int ga = ((fg ^ ((fr >> 1) & 3)) << 4);        // bytes

  auto stageA = [&](int kt) {
    u8* ad = smem + (kt & 3) * 16384 + wave * 1024;
    gload16(Ag + kbeg + (kt << 6), ad);
    gload16(Ag2 + kbeg + (kt << 6), ad + 8192);
  };
  auto stageB = [&](int kt) {
    u8* bd = smem + 65536 + (kt & 3) * 16384 + wave * 1024;
    gload16(Bg + kbeg + (kt << 6), bd);
    gload16(Bg2 + kbeg + (kt << 6), bd + 8192);
  };

  constexpr int NT = 16;
  stageA(0); stageB(0); stageA(1); stageB(1); stageA(2); stageB(2);
  asm volatile("s_waitcnt vmcnt(8)" ::: "memory");
  __builtin_amdgcn_s_barrier();
  asm volatile("" ::: "memory");
  i32x4 bf[4], af[4];
  for (int kt = 0; kt < NT; ++kt) {
    const u8* Ab = smem + (kt & 3) * 16384;
    const u8* Bb = smem + 65536 + (kt & 3) * 16384;
    const bool st = (kt < NT - 3);
    // phase A
#pragma unroll
    for (int n = 0; n < 4; ++n)
      bf[n] = *(const i32x4*)&Bb[(wc + n * 16 + fr) * 64 + ga];
#pragma unroll
    for (int m = 0; m < 4; ++m)
      af[m] = *(const i32x4*)&Ab[(wr + m * 16 + fr) * 64 + ga];
    if (st) stageA(kt + 3);
    __builtin_amdgcn_s_barrier();
    asm volatile("" ::: "memory");
    __builtin_amdgcn_s_setprio(1);
#pragma unroll
    for (int m = 0; m < 4; ++m)
#pragma unroll
      for (int n = 0; n < 4; ++n)
        acc[m][n] = __builtin_amdgcn_mfma_i32_16x16x64_i8(af[m], bf[n], acc[m][n], 0, 0, 0);
    __builtin_amdgcn_s_setprio(0);
    // phase B
#pragma unroll
    for (int m = 0; m < 4; ++m)
      af[m] = *(const i32x4*)&Ab[(wr + (m + 4) * 16 + fr) * 64 + ga];
    if (st) stageB(kt + 3);
    if (kt < NT - 3) {
      asm volatile("s_waitcnt vmcnt(8)" ::: "memory");
    } else if (kt == NT - 3) {
      asm volatile("s_waitcnt vmcnt(4)" ::: "memory");
    } else if (kt == NT - 2) {
      asm volatile("s_waitcnt vmcnt(0)" ::: "memory");
    }
    __builtin_amdgcn_s_barrier();
    asm volatile("" ::: "memory");
    __builtin_amdgcn_s_setprio(1);
#pragma unroll
    for (int m = 0; m < 4; ++m)
#pragma unroll
      for (int n = 0; n < 4; ++n)
        acc[m + 4][n] = __builtin_amdgcn_mfma_i32_16x16x64_i8(af[m], bf[n], acc[m + 4][n], 0, 0, 0);
    __builtin_amdgcn_s_setprio(0);
  }

  const int fq = lane >> 4;
#pragma unroll
  for (int m = 0; m < 8; ++m)
#pragma unroll
    for (int n = 0; n < 4; ++n)
#pragma unroll
      for (int j = 0; j < 4; ++j) {
        int rl = wr + m * 16 + fq * 4 + j;
        int cl = wc + n * 16 + fr;
        pout[(size_t)(bm + rl) * Hn + bn + cl] = (float)acc[m][n][j];
      }
}

// ---------------- merged G2+G3 (512 blocks, one launch) -------------------
__global__ __launch_bounds__(512) void g23_k(
    const u16* __restrict__ A2, const u16* __restrict__ B2,
    const u16* __restrict__ aux16, const float* __restrict__ bias2,
    float* __restrict__ redp2,
    const u16* __restrict__ A3, const u16* __restrict__ B3,
    float* __restrict__ out30, float* __restrict__ out34) {
  __shared__ __align__(16) u16 smem[65536];
  const int t = threadIdx.x;
  const int lane = t & 63, wave = t >> 6;
  const int wr = (wave >> 2) << 7;
  const int wc = (wave & 3) << 6;
  const int flat = blockIdx.x;
  const bool isG2 = (flat < 256);
  int bidx, bidy, bidz = 0;
  const u16 *Abase, *Bbase;
  int lda, ldb;
  if (isG2) {
    bidx = flat & 31; bidy = flat >> 5;
    Abase = A2; Bbase = B2; lda = Hn; ldb = 2 * Hn;
  } else {
    const int orig = flat - 256;
    bidz = orig & 7;
    const int rr = orig >> 3;          // 0..31 rank within XCD
    bidx = rr & 7; bidy = rr >> 3;
    Abase = A3 + (size_t)bidz * 1024;
    Bbase = B3 + (size_t)bidz * 1024;
    lda = Bn; ldb = Bn;
  }
  const int bm = bidx << 8, bn = bidy << 8;
  f32x4 acc[8][4] = {};
  const int sr = t >> 2;
  const int sc = (((t & 3) ^ ((t >> 3) & 3)) << 3);
  const u16* Ag  = Abase + (size_t)(bm + sr) * lda + sc;
  const u16* Ag2 = Ag + (size_t)128 * lda;
  const u16* Bg  = Bbase + (size_t)(bn + sr) * ldb + sc;
  const u16* Bg2 = Bg + (size_t)128 * ldb;
  const int fr = lane & 15, fg = lane >> 4;
  const int ga = ((fg ^ ((fr >> 1) & 3)) << 3);

  auto stageA = [&](int kt) {
    u16* ad = smem + (kt & 3) * 8192 + wave * 512;
    gload16(Ag + (kt << 5), ad);
    gload16(Ag2 + (kt << 5), ad + 4096);
  };
  auto stageB = [&](int kt) {
    u16* bd = smem + 32768 + (kt & 3) * 8192 + wave * 512;
    gload16(Bg + (kt << 5), bd);
    gload16(Bg2 + (kt << 5), bd + 4096);
  };
  auto pfl2 = [&](int ci) -> unsigned {
    const int L = (ci << 9) + t;         // 0..1023
    return (unsigned)aux16[(size_t)(bm + (L >> 2)) * 4096 + bn + ((L & 3) << 6)];
  };

  constexpr int NT = 32;
  stageA(0); stageB(0); stageA(1); stageB(1); stageA(2); stageB(2);
  asm volatile("s_waitcnt vmcnt(8)" ::: "memory");
  __builtin_amdgcn_s_barrier();
  asm volatile("" ::: "memory");
  s16x8 bf[4], af[4];
  for (int kt = 0; kt < NT; ++kt) {
    const int pb = kt & 3;
    const u16* Ab = smem + pb * 8192;
    const u16* Bb = smem + 32768 + pb * 8192;
    const bool st = (kt < NT - 3);
    // phase A
#pragma unroll
    for (int n = 0; n < 4; ++n)
      bf[n] = *(const s16x8*)&Bb[(wc + n * 16 + fr) * 32 + ga];
#pragma unroll
    for (int m = 0; m < 4; ++m)
      af[m] = *(const s16x8*)&Ab[(wr + m * 16 + fr) * 32 + ga];
    if (st) stageA(kt + 3);
    if (isG2 && kt >= NT - 8 && kt < NT - 6) {
      unsigned pfv = pfl2(kt - (NT - 8));
      asm volatile("" :: "v"(pfv));
    }
    __builtin_amdgcn_s_barrier();
    asm volatile("" ::: "memory");
    __builtin_amdgcn_s_setprio(1);
#pragma unroll
    for (int m = 0; m < 4; ++m)
#pragma unroll
      for (int n = 0; n < 4; ++n)
        acc[m][n] = __builtin_amdgcn_mfma_f32_16x16x32_bf16(af[m], bf[n], acc[m][n], 0, 0, 0);
    __builtin_amdgcn_s_setprio(0);
    // phase B
#pragma unroll
    for (int m = 0; m < 4; ++m)
      af[m] = *(const s16x8*)&Ab[(wr + (m + 4) * 16 + fr) * 32 + ga];
    if (st) stageB(kt + 3);
    if (kt < NT - 3) {
      asm volatile("s_waitcnt vmcnt(8)" ::: "memory");
    } else if (kt == NT - 3) {
      asm volatile("s_waitcnt vmcnt(4)" ::: "memory");
    } else if (kt == NT - 2) {
      asm volatile("s_waitcnt vmcnt(0)" ::: "memory");
    }
    __builtin_amdgcn_s_barrier();
    asm volatile("" ::: "memory");
    __builtin_amdgcn_s_setprio(1);
#pragma unroll
    for (int m = 0; m < 4; ++m)
#pragma unroll
      for (int n = 0; n < 4; ++n)
        acc[m + 4][n] = __builtin_amdgcn_mfma_f32_16x16x32_bf16(af[m], bf[n], acc[m + 4][n], 0, 0, 0);
    __builtin_amdgcn_s_setprio(0);
  }

  const int fq = lane >> 4;
  if (isG2) {
    // pipelined recon vs v_cat-hi (u16, stride 4096), depth-8 window (&7).
    float bcol[4];
#pragma unroll
    for (int n = 0; n < 4; ++n) bcol[n] = bias2[bn + wc + n * 16 + fr];
    const size_t ebase = (size_t)(bm + wr + fq * 4) * 4096 + (bn + wc + fr);
    float ax[8][4];
    auto ld4 = [&](int ci, float* dst) {
      size_t e0 = ebase + (size_t)((ci >> 2) << 4) * 4096 + ((ci & 3) << 4);
      dst[0] = bf2f(aux16[e0]);            dst[1] = bf2f(aux16[e0 + 4096]);
      dst[2] = bf2f(aux16[e0 + 2 * 4096]); dst[3] = bf2f(aux16[e0 + 3 * 4096]);
    };
#pragma unroll
    for (int ci = 0; ci < 8; ++ci) ld4(ci, ax[ci]);
#pragma unroll
    for (int m = 0; m < 8; ++m)
#pragma unroll
      for (int n = 0; n < 4; ++n)
#pragma unroll
        for (int j = 0; j < 4; ++j)
          acc[m][n][j] = sigmoidf_(acc[m][n][j] + bcol[n]);
    float lsum = 0.f;
#pragma unroll
    for (int ci = 0; ci < 32; ++ci) {
      const int m = ci >> 2, n = ci & 3;
#pragma unroll
      for (int j = 0; j < 4; ++j) lsum += fabsf(ax[ci & 7][j] - acc[m][n][j]);
      if (ci < 24) ld4(ci + 8, ax[ci & 7]);
    }
#pragma unroll
    for (int off = 32; off > 0; off >>= 1) lsum += __shfl_down(lsum, off);
    __syncthreads();
    float* redlds = (float*)smem;
    if (lane == 0) redlds[wave] = lsum;
    __syncthreads();
    if (t == 0) {
      float s = 0.f;
#pragma unroll
      for (int wv = 0; wv < 8; ++wv) s += redlds[wv];
      redp2[(size_t)bidy * 32 + bidx] = s;
    }
  } else {
    float* pout = ((bidz < 4) ? out30 : out34) + (size_t)(bidz & 3) * VH;
#pragma unroll
    for (int m = 0; m < 8; ++m)
#pragma unroll
      for (int n = 0; n < 4; ++n)
#pragma unroll
        for (int j = 0; j < 4; ++j) {
          int rl = wr + m * 16 + fq * 4 + j;
          int cl = wc + n * 16 + fr;
          pout[(size_t)(bm + rl) * Hn + bn + cl] = acc[m][n][j];
        }
  }
}

// merged tail: blocks <2048 = reduce8s (w_grad = model partials - data grad),
// blocks >=2048 (8) = finalize (bias grads + recon scalar).
__global__ void tail_k(const float* __restrict__ pa, const float* __restrict__ pb,
                       const float* __restrict__ sums, float* __restrict__ out) {
  const int b = blockIdx.x;
  float* outw = out + OUT_WGRAD;
  if (b < 2048) {
    size_t e = ((size_t)b * 256 + threadIdx.x) * 4;
    f32x4 r = {};
#pragma unroll
    for (int z = 0; z < 4; ++z) r += *(const f32x4*)&pa[(size_t)z * VH + e];
#pragma unroll
    for (int z = 0; z < 4; ++z) r += *(const f32x4*)&pb[(size_t)z * VH + e];
    float s0 = outw[e + 0], s1 = outw[e + 1], s2 = outw[e + 2], s3 = outw[e + 3];
    outw[e + 0] = r[0] - s0; outw[e + 1] = r[1] - s1;
    outw[e + 2] = r[2] - s2; outw[e + 3] = r[3] - s3;
  } else {
    const int i = (b - 2048) * 256 + threadIdx.x;   // 0..2047
    const float* recon_p = sums;                 // 256
    const float* vbd = sums + 1024;              // 128 x 2048
    const float* hbd = vbd + 128 * 2048;         // 128 x 1024
    const float* vbm = hbd + 128 * 1024;         // 64 x 2048
    const float* hbm = vbm + 128 * 2048;         // 128 x 1024
    if (i < 2048) {
      float d = 0.f, m = 0.f;
      for (int k = 0; k < 128; ++k) d += vbd[k * 2048 + i];
      for (int k = 0; k < 64; ++k)  m += vbm[k * 2048 + i];
      out[OUT_VBG + i] = m - d;
    }
    if (i < 1024) {
      float d = 0.f, m = 0.f;
      for (int k = 0; k < 128; ++k) { d += hbd[k * 1024 + i]; m += hbm[k * 1024 + i]; }
      out[OUT_HBG + i] = m - d;
    }
    if (i == 0) {
      float s = 0.f;
      for (int k = 0; k < 256; ++k) s += recon_p[k];
      out[OUT_RECON] = s * (1.0f / 16777216.0f);  // /(B*V)
    }
  }
}

extern "C" void kernel_launch(void* const* d_in, const int* in_sizes, int n_in,
                              void* d_out, int out_size, void* d_ws, size_t ws_size,
                              hipStream_t stream) {
  (void)in_sizes; (void)n_in; (void)out_size;
  const float* v   = (const float*)d_in[0];
  const float* w   = (const float*)d_in[1];
  const float* vb  = (const float*)d_in[2];
  const float* hb  = (const float*)d_in[3];
  const float* u_h = (const float*)d_in[4];
  const float* u_v = (const float*)d_in[5];
  float* out = (float*)d_out;
  char* ws = (char*)d_ws;
  if (ws_size < 204734464ULL) return;

  float* sums    = (float*)ws;               // 3.25 MiB region
  float* recon_p = sums;                     // 256
  float* vbd_p   = sums + 1024;              // 128*2048
  float* hbd_p   = vbd_p + 128 * 2048;       // 128*1024
  float* vbm_p   = hbd_p + 128 * 1024;       // 64*2048
  float* hbm_p   = vbm_p + 128 * 2048;       // 128*1024
  char* p = ws + 3407872;
  u16* v_cat  = (u16*)p;  p += (size_t)Bn * 2 * Vn * 2;   // 64 MiB [B,2V]
  u16* wT_cat = (u16*)p;  p += (size_t)Hn * 2 * Vn * 2;   // 8 MiB [H,2V]
  u16* w_cat  = (u16*)p;  p += (size_t)Vn * 2 * Hn * 2;   // 8 MiB [V,2H]
  u16* h_p    = (u16*)p;  p += BH * 2;                    // 16 MiB [B,H]
  u16* hbin   = (u16*)p;  p += BH * 2;                    // 16 MiB [B,H]
  u16* vT     = (u16*)p;  p += (size_t)Vn * Bn * 2;       // 32 MiB [V,B]
  u16* hT     = (u16*)p;  p += (size_t)Hn * Bn * 2;       // 16 MiB [H,B]
  float* big  = (float*)p;                                // 32 MiB time-shared
  u8*  vkT8 = (u8*)vT;          // vT dead after g23; u8 vkT (16 MiB used)
  u8*  h2T8 = (u8*)hT;          // hT dead after g23; u8 h2T (8 MiB used)
  float* vcat_f = (float*)v_cat;   // 64 MiB: G3's 8 partials
  float* hpbuf  = (float*)h_p;     // h_p+hbin region (32 MiB) as f32 partials
  u16* vk   = (u16*)big;           // vk now lives in big (free epi1 -> G5a)
  float* g5z1  = vcat_f + 4 * VH;  // G5a z1 partials (free after reduce8)
  float* outW   = out + OUT_WGRAD;

  prep_all_k<<<4608, 256, 0, stream>>>(v, v_cat, vT, vbd_p, w, w_cat, wT_cat);
  // G1a: split-K x2 partials (z0 -> out[0..BH) scratch, z1 -> big)
  gemm256<1><<<dim3(32, 4, 2), 512, 0, stream>>>(
      v_cat, 2 * Vn, wT_cat, 2 * Vn, 3072, out, big);
  // epi: h_pred / h_p / hbin / hT / hbd
  epi_h_k<1><<<dim3(128, 16), 256, 0, stream>>>(
      out, big, hb, u_h, out, h_p, hbin, hT, hbd_p);
  // merged G2 (recon) + G3 (w_data_grad partials): 512 blocks, one launch
  g23_k<<<512, 512, 0, stream>>>(
      h_p, w_cat, v_cat, vb, recon_p,
      vT, hT, vcat_f, vcat_f + 4 * VH);
  // merged reduce8 (outW = data-grad sum) + G4 (vk->big / vkT8 / vbm)
  g4red_k<<<1280, 512, 0, stream>>>(
      vcat_f, outW, hbin, w_cat, vb, u_v, vk, (u16*)vkT8, vbm_p);
  // G5a: split-K x2 partials (z0 -> hpbuf, z1 -> g5z1)
  gemm256<5><<<dim3(32, 4, 2), 512, 0, stream>>>(
      vk, Vn, wT_cat, 2 * Vn, 2048, hpbuf, g5z1);
  // epi: h2T (u8) + hbm
  epi_h_k<5><<<dim3(128, 16), 256, 0, stream>>>(
      hpbuf, g5z1, hb, u_h + BH, nullptr, nullptr, nullptr, (u16*)h2T8, hbm_p);
  // G6: w_model_grad partials via i8 MFMA (exact; split-K x8: z<4 -> hpbuf,
  // z>=4 -> big; vk dead after G5a)
  gemm_i8_k<<<dim3(8, 4, 8), 512, 0, stream>>>(vkT8, h2T8, hpbuf, big);
  // merged reduce8s + finalize
  tail_k<<<2056, 256, 0, stream>>>(hpbuf, big, sums, out);
}